// Round 6
// baseline (957.413 us; speedup 1.0000x reference)
//
#include <hip/hip_runtime.h>
#include <hip/hip_bf16.h>

#define NN 100000
#define NE 1600000
#define IN_DIM 33
#define HID 128
#define NG 128
#define NCLS 10

static __device__ __forceinline__ size_t szmul(int a, int b) {
    return (size_t)a * (size_t)b;
}

// ---------------- init ----------------
__global__ void k_init(int* cnt, int* fill, float* gsum, int n) {
    int i = blockIdx.x * blockDim.x + threadIdx.x;
    if (i < n) { cnt[i] = 0; fill[i] = 0; }
    if (i < NG * HID) gsum[i] = 0.0f;
}

// ---------------- CSR build ----------------
__global__ void k_edge_count(const int* __restrict__ col, int* cnt, int e) {
    int i = blockIdx.x * blockDim.x + threadIdx.x;
    if (i < e) atomicAdd(&cnt[col[i]], 1);
}

#define SCAN_B 1024
__global__ void k_scan1(const int* __restrict__ cnt, int* __restrict__ rowptr,
                        int* __restrict__ bsums, int n) {
    __shared__ int s[SCAN_B];
    int t = threadIdx.x;
    int i = blockIdx.x * SCAN_B + t;
    int v = (i < n) ? cnt[i] : 0;
    s[t] = v;
    __syncthreads();
    for (int o = 1; o < SCAN_B; o <<= 1) {
        int a = (t >= o) ? s[t - o] : 0;
        __syncthreads();
        s[t] += a;
        __syncthreads();
    }
    if (i < n) rowptr[i] = s[t] - v;          // exclusive within block
    if (t == SCAN_B - 1) bsums[blockIdx.x] = s[t];
}

__global__ void k_scan2(int* bsums, int nb) {
    if (threadIdx.x == 0 && blockIdx.x == 0) {
        int run = 0;
        for (int b = 0; b < nb; ++b) { int v = bsums[b]; bsums[b] = run; run += v; }
    }
}

__global__ void k_scan3(int* rowptr, const int* __restrict__ bsums, int n, int etot) {
    int i = blockIdx.x * blockDim.x + threadIdx.x;
    if (i < n) rowptr[i] += bsums[i >> 10];
    else if (i == n) rowptr[n] = etot;
}

// scatter RAW weights, packed (src, w_bits) in one 8B store
__global__ void k_edge_scatter(const int* __restrict__ row, const int* __restrict__ col,
                               const float* __restrict__ w,
                               const int* __restrict__ rowptr, int* fill,
                               int2* __restrict__ csr, int e) {
    int i = blockIdx.x * blockDim.x + threadIdx.x;
    if (i < e) {
        int c = col[i];
        int pos = rowptr[c] + atomicAdd(&fill[c], 1);
        csr[pos] = make_int2(row[i], __float_as_int(w[i]));
    }
}

// deg[i] = 1 (self loop) + sum of raw weights into i; dinv = deg^-1/2
__global__ void k_deg(const int* __restrict__ rowptr, const int2* __restrict__ csr,
                      float* __restrict__ dinv, float* __restrict__ selfn, int n) {
    int i = blockIdx.x * blockDim.x + threadIdx.x;
    if (i >= n) return;
    int beg = rowptr[i], end = rowptr[i + 1];
    float d = 1.0f;
    for (int e = beg; e < end; ++e) d += __int_as_float(csr[e].y);
    float di = (d > 0.0f) ? (1.0f / sqrtf(d)) : 0.0f;
    dinv[i] = di;
    selfn[i] = di * di;
}

// csr_w[e] = dinv[src]*w*dinv[dst]; also s[i] = selfn[i] + sum(normalized w) = row-sum of A
__global__ void k_norm(const int* __restrict__ rowptr, int2* __restrict__ csr,
                       const float* __restrict__ dinv, const float* __restrict__ selfn,
                       float* __restrict__ s, int n) {
    int i = blockIdx.x * blockDim.x + threadIdx.x;
    if (i >= n) return;
    float dc = dinv[i];
    float acc = selfn[i];
    int beg = rowptr[i], end = rowptr[i + 1];
    for (int e = beg; e < end; ++e) {
        int2 v = csr[e];
        float nw = dinv[v.x] * __int_as_float(v.y) * dc;
        csr[e] = make_int2(v.x, __float_as_int(nw));
        acc += nw;
    }
    s[i] = acc;
}

// ---------------- fused weights: M = We@W1 [33x128], v = be@W1 [128] ----------------
__global__ void k_combine(const float* __restrict__ We, const float* __restrict__ W1,
                          const float* __restrict__ be,
                          float* __restrict__ M, float* __restrict__ v) {
    int f = threadIdx.x;            // 128
    int k = blockIdx.x;             // 0..33; 33 => bias row
    if (k < IN_DIM) {
        float a = 0.0f;
#pragma unroll 8
        for (int j = 0; j < HID; ++j) a += We[k * HID + j] * W1[j * HID + f];
        M[k * HID + f] = a;
    } else {
        float a = 0.0f;
#pragma unroll 8
        for (int j = 0; j < HID; ++j) a += be[j] * W1[j * HID + f];
        v[f] = a;
    }
}

// ---------------- Y = A @ x  (33-dim aggregate, incl self loop) ----------------
// edge record read directly (uniform -> L1 broadcast), no shfl; unrolled for MLP depth
__global__ __launch_bounds__(256) void k_agg_x(const float* __restrict__ x,
                                               const int* __restrict__ rowptr,
                                               const int2* __restrict__ csr,
                                               const float* __restrict__ selfn,
                                               float* __restrict__ Y, int n) {
    int i = (blockIdx.x * 256 + threadIdx.x) >> 6;
    if (i >= n) return;
    int lane = threadIdx.x & 63;
    float a = 0.0f;
    if (lane < IN_DIM) a = selfn[i] * x[szmul(i, IN_DIM) + lane];
    int beg = rowptr[i], end = rowptr[i + 1];
#pragma unroll 4
    for (int j = beg; j < end; ++j) {
        int2 e = csr[j];                         // uniform across wave -> one transaction
        float wj = __int_as_float(e.y);
        if (lane < IN_DIM) a += wj * x[szmul(e.x, IN_DIM) + lane];
    }
    if (lane < IN_DIM) Y[szmul(i, IN_DIM) + lane] = a;
}

// ---------------- h = relu(Y@M + s*v + b1)  (N x 33 @ 33 x 128) ----------------
__global__ __launch_bounds__(256) void k_gemm33(const float* __restrict__ Y,
                                                const float* __restrict__ M,
                                                const float* __restrict__ v,
                                                const float* __restrict__ s,
                                                const float* __restrict__ b1,
                                                float* __restrict__ h, int n) {
    __shared__ float sY[32 * IN_DIM];
    __shared__ float ss[32];
    int n0 = blockIdx.x * 32;
    int tid = threadIdx.x;
    int cnt = n - n0; if (cnt > 32) cnt = 32;
    for (int idx = tid; idx < cnt * IN_DIM; idx += 256)
        sY[idx] = Y[szmul(n0, IN_DIM) + idx];
    if (tid < cnt) ss[tid] = s[n0 + tid];
    __syncthreads();
    int f = tid & 127, g = tid >> 7;
    float Mc[IN_DIM];
#pragma unroll
    for (int k = 0; k < IN_DIM; ++k) Mc[k] = M[k * HID + f];
    float vf = v[f], bf = b1[f];
    int ndEnd = g * 16 + 16; if (ndEnd > cnt) ndEnd = cnt;
    for (int nd = g * 16; nd < ndEnd; ++nd) {
        float a = bf + ss[nd] * vf;
#pragma unroll
        for (int k = 0; k < IN_DIM; ++k) a += sY[nd * IN_DIM + k] * Mc[k];
        h[szmul(n0 + nd, HID) + f] = fmaxf(a, 0.0f);
    }
}

// ---------------- GEMM: C = A @ W  (A: n x 128, W: 128 x 128) ----------------
__global__ __launch_bounds__(256) void k_gemm(const float* __restrict__ A,
                                              const float* __restrict__ W,
                                              float* __restrict__ C, int n) {
    __shared__ float sA[64][HID];   // 32 KiB
    int b0 = blockIdx.x * 64;
    int tid = threadIdx.x;
#pragma unroll
    for (int u = 0; u < 8; ++u) {
        int idx = u * 256 + tid;
        int r = idx >> 5, c4 = idx & 31;
        float4 v = make_float4(0.f, 0.f, 0.f, 0.f);
        if (b0 + r < n)
            v = *reinterpret_cast<const float4*>(A + szmul(b0 + r, HID) + c4 * 4);
        *reinterpret_cast<float4*>(&sA[r][c4 * 4]) = v;
    }
    __syncthreads();
    int ty = tid >> 5, tx = tid & 31;
    float acc0[8], acc1[8], acc2[8], acc3[8];
#pragma unroll
    for (int j = 0; j < 8; ++j) { acc0[j] = 0.f; acc1[j] = 0.f; acc2[j] = 0.f; acc3[j] = 0.f; }
    const float* Wp = W + tx * 4;
#pragma unroll 2
    for (int k = 0; k < HID; ++k) {
        float4 w4 = *reinterpret_cast<const float4*>(Wp + (size_t)k * HID);
#pragma unroll
        for (int j = 0; j < 8; ++j) {
            float a = sA[ty * 8 + j][k];
            acc0[j] += a * w4.x;
            acc1[j] += a * w4.y;
            acc2[j] += a * w4.z;
            acc3[j] += a * w4.w;
        }
    }
#pragma unroll
    for (int j = 0; j < 8; ++j) {
        int r = b0 + ty * 8 + j;
        if (r < n) {
            float4 o = make_float4(acc0[j], acc1[j], acc2[j], acc3[j]);
            *reinterpret_cast<float4*>(&C[szmul(r, HID) + tx * 4]) = o;
        }
    }
}

// ---------------- aggregate: h[i] = relu(b + selfn[i]*t[i] + sum_e w_e * t[src_e]) ----
// wave per node; halves process edges j and j+1; edge records read directly from
// global (uniform per half -> one 16B transaction, L1-resident). No cross-lane ops
// in the loop -> iterations independent -> deep memory pipelining via unroll.
__global__ __launch_bounds__(256) void k_aggregate(const float* __restrict__ t,
                                                   const int* __restrict__ rowptr,
                                                   const int2* __restrict__ csr,
                                                   const float* __restrict__ selfn,
                                                   const float* __restrict__ bias,
                                                   float* __restrict__ hout, int n) {
    int i = (blockIdx.x * 256 + threadIdx.x) >> 6;
    if (i >= n) return;
    int lane = threadIdx.x & 63;
    int half = lane >> 5;
    int f0 = (lane & 31) << 2;
    float a0 = 0.f, a1 = 0.f, a2 = 0.f, a3 = 0.f;
    if (half == 0) {
        float4 sf = *reinterpret_cast<const float4*>(&t[szmul(i, HID) + f0]);
        float4 b4 = *reinterpret_cast<const float4*>(&bias[f0]);
        float sn = selfn[i];
        a0 = b4.x + sn * sf.x; a1 = b4.y + sn * sf.y;
        a2 = b4.z + sn * sf.z; a3 = b4.w + sn * sf.w;
    }
    int beg = rowptr[i], end = rowptr[i + 1];
#pragma unroll 4
    for (int j = beg; j < end; j += 2) {
        int jj = j + half;                       // lanes 0-31: edge j, 32-63: edge j+1
        int2 e = (jj < end) ? csr[jj] : make_int2(0, 0);
        float wj = __int_as_float(e.y);
        float4 tv = *reinterpret_cast<const float4*>(&t[szmul(e.x, HID) + f0]);
        a0 += wj * tv.x; a1 += wj * tv.y; a2 += wj * tv.z; a3 += wj * tv.w;
    }
    a0 += __shfl_xor(a0, 32); a1 += __shfl_xor(a1, 32);
    a2 += __shfl_xor(a2, 32); a3 += __shfl_xor(a3, 32);
    if (half == 0) {
        float4 o = make_float4(fmaxf(a0, 0.f), fmaxf(a1, 0.f),
                               fmaxf(a2, 0.f), fmaxf(a3, 0.f));
        *reinterpret_cast<float4*>(&hout[szmul(i, HID) + f0]) = o;
    }
}

// ---------------- pooling ----------------
__global__ void k_gcount_bs(const int* __restrict__ batch, int* gcnt, int n) {
    int g = threadIdx.x;
    if (g >= NG) return;
    int lo = 0, hi = n;
    while (lo < hi) { int mid = (lo + hi) >> 1; if (batch[mid] < g) lo = mid + 1; else hi = mid; }
    int start = lo;
    lo = 0; hi = n;
    while (lo < hi) { int mid = (lo + hi) >> 1; if (batch[mid] < g + 1) lo = mid + 1; else hi = mid; }
    gcnt[g] = lo - start;
}

__global__ __launch_bounds__(128) void k_pool(const float* __restrict__ h,
                                              const int* __restrict__ batch,
                                              float* gsum, int n) {
    int f = threadIdx.x;
    int i0 = blockIdx.x * 32;
    int i1 = min(i0 + 32, n);
    if (i0 >= n) return;
    float acc = 0.0f;
    int cur = batch[i0];
    for (int i = i0; i < i1; ++i) {
        int g = batch[i];
        if (g != cur) { atomicAdd(&gsum[cur * HID + f], acc); acc = 0.0f; cur = g; }
        acc += h[szmul(i, HID) + f];
    }
    atomicAdd(&gsum[cur * HID + f], acc);
}

// ---------------- readout MLP ----------------
__global__ __launch_bounds__(128) void k_mlp(const float* __restrict__ gsum,
                                             const int* __restrict__ gcnt,
                                             const float* __restrict__ Wr1, const float* __restrict__ br1,
                                             const float* __restrict__ Wr2, const float* __restrict__ br2,
                                             const float* __restrict__ Wr3,
                                             float* __restrict__ out) {
    int g = blockIdx.x;
    int t = threadIdx.x;
    __shared__ float p[HID];
    __shared__ float r1[64];
    __shared__ float r2[32];
    float c = fmaxf((float)gcnt[g], 1.0f);
    p[t] = gsum[g * HID + t] / c;
    __syncthreads();
    if (t < 64) {
        float a = br1[t];
#pragma unroll 8
        for (int k = 0; k < HID; ++k) a += p[k] * Wr1[k * 64 + t];
        r1[t] = fmaxf(a, 0.0f);
    }
    __syncthreads();
    if (t < 32) {
        float a = br2[t];
#pragma unroll 8
        for (int k = 0; k < 64; ++k) a += r1[k] * Wr2[k * 32 + t];
        r2[t] = fmaxf(a, 0.0f);
    }
    __syncthreads();
    if (t < NCLS) {
        float a = 0.0f;
#pragma unroll
        for (int k = 0; k < 32; ++k) a += r2[k] * Wr3[k * NCLS + t];
        out[g * NCLS + t] = a;
    }
}

extern "C" void kernel_launch(void* const* d_in, const int* in_sizes, int n_in,
                              void* d_out, int out_size, void* d_ws, size_t ws_size,
                              hipStream_t stream) {
    const float* x     = (const float*)d_in[0];
    const int*   ei    = (const int*)d_in[1];
    const float* ew    = (const float*)d_in[2];
    const int*   batch = (const int*)d_in[3];
    const float* We  = (const float*)d_in[4];
    const float* be  = (const float*)d_in[5];
    const float* Wl[4] = { (const float*)d_in[6], (const float*)d_in[8],
                           (const float*)d_in[10], (const float*)d_in[12] };
    const float* bl[4] = { (const float*)d_in[7], (const float*)d_in[9],
                           (const float*)d_in[11], (const float*)d_in[13] };
    const float* Wr1 = (const float*)d_in[14];
    const float* br1 = (const float*)d_in[15];
    const float* Wr2 = (const float*)d_in[16];
    const float* br2 = (const float*)d_in[17];
    const float* Wr3 = (const float*)d_in[18];
    float* out = (float*)d_out;

    const int N = in_sizes[3];      // 100000
    const int E = in_sizes[2];      // 1600000
    const int* row = ei;
    const int* col = ei + E;

    // workspace layout
    char* w = (char*)d_ws;
    size_t off = 0;
    auto alloc = [&](size_t bytes) -> void* {
        void* p = w + off;
        off = (off + bytes + 255) & ~(size_t)255;
        return p;
    };
    float* dinv    = (float*)alloc((size_t)N * 4);
    float* selfn   = (float*)alloc((size_t)N * 4);
    float* srow    = (float*)alloc((size_t)N * 4);       // row-sums of A
    int*   cnt     = (int*)  alloc((size_t)N * 4);
    int*   rowptr  = (int*)  alloc((size_t)(N + 1) * 4);
    int*   fill    = (int*)  alloc((size_t)N * 4);
    int*   bsums   = (int*)  alloc(4096);
    int2*  csr     = (int2*) alloc((size_t)E * 8);
    float* h       = (float*)alloc((size_t)N * HID * 4);
    float* t       = (float*)alloc((size_t)N * HID * 4);
    float* M       = (float*)alloc((size_t)IN_DIM * HID * 4);
    float* vbe     = (float*)alloc((size_t)HID * 4);
    float* gsum    = (float*)alloc((size_t)NG * HID * 4);
    int*   gcnt    = (int*)  alloc((size_t)NG * 4);
    float* Y       = t;   // alias: Y[N][33] consumed before t is first written
    (void)ws_size;

    auto cdiv = [](int a, int b) { return (a + b - 1) / b; };

    k_init<<<cdiv(N, 256), 256, 0, stream>>>(cnt, fill, gsum, N);
    k_edge_count<<<cdiv(E, 256), 256, 0, stream>>>(col, cnt, E);

    int nb = cdiv(N, SCAN_B);
    k_scan1<<<nb, SCAN_B, 0, stream>>>(cnt, rowptr, bsums, N);
    k_scan2<<<1, 64, 0, stream>>>(bsums, nb);
    k_scan3<<<cdiv(N + 1, 256), 256, 0, stream>>>(rowptr, bsums, N, E);
    k_edge_scatter<<<cdiv(E, 256), 256, 0, stream>>>(row, col, ew, rowptr, fill, csr, E);
    k_deg<<<cdiv(N, 256), 256, 0, stream>>>(rowptr, csr, dinv, selfn, N);
    k_norm<<<cdiv(N, 256), 256, 0, stream>>>(rowptr, csr, dinv, selfn, srow, N);

    // layer 1, restructured: h = relu((A x)(We W1) + s*(be W1) + b1)
    k_combine<<<IN_DIM + 1, HID, 0, stream>>>(We, Wl[0], be, M, vbe);
    k_agg_x<<<cdiv(N, 4), 256, 0, stream>>>(x, rowptr, csr, selfn, Y, N);
    k_gemm33<<<cdiv(N, 32), 256, 0, stream>>>(Y, M, vbe, srow, bl[0], h, N);

    // layers 2-4
    for (int l = 1; l < 4; ++l) {
        k_gemm<<<cdiv(N, 64), 256, 0, stream>>>(h, Wl[l], t, N);
        k_aggregate<<<cdiv(N, 4), 256, 0, stream>>>(t, rowptr, csr, selfn, bl[l], h, N);
    }

    k_gcount_bs<<<1, 128, 0, stream>>>(batch, gcnt, N);
    k_pool<<<cdiv(N, 32), 128, 0, stream>>>(h, batch, gsum, N);
    k_mlp<<<NG, HID, 0, stream>>>(gsum, gcnt, Wr1, br1, Wr2, br2, Wr3, out);

    (void)out_size; (void)n_in;
}

// Round 7
// 785.781 us; speedup vs baseline: 1.2184x; 1.2184x over previous
//
#include <hip/hip_runtime.h>
#include <hip/hip_bf16.h>

#define NN 100000
#define NE 1600000
#define IN_DIM 33
#define HID 128
#define NG 128
#define NCLS 10

static __device__ __forceinline__ size_t szmul(int a, int b) {
    return (size_t)a * (size_t)b;
}

// bf16 helpers: pack with RNE, unpack via bit ops (cheap: 1 VALU each)
static __device__ __forceinline__ unsigned short f2bf(float f) {
    unsigned u = __float_as_uint(f);
    u += 0x7fffu + ((u >> 16) & 1u);
    return (unsigned short)(u >> 16);
}
static __device__ __forceinline__ float bf_lo(unsigned u) { return __uint_as_float(u << 16); }
static __device__ __forceinline__ float bf_hi(unsigned u) { return __uint_as_float(u & 0xffff0000u); }

// ---------------- init ----------------
__global__ void k_init(int* cnt, int* fill, float* gsum, int n) {
    int i = blockIdx.x * blockDim.x + threadIdx.x;
    if (i < n) { cnt[i] = 0; fill[i] = 0; }
    if (i < NG * HID) gsum[i] = 0.0f;
}

// ---------------- CSR build ----------------
__global__ void k_edge_count(const int* __restrict__ col, int* cnt, int e) {
    int i = blockIdx.x * blockDim.x + threadIdx.x;
    if (i < e) atomicAdd(&cnt[col[i]], 1);
}

#define SCAN_B 1024
__global__ void k_scan1(const int* __restrict__ cnt, int* __restrict__ rowptr,
                        int* __restrict__ bsums, int n) {
    __shared__ int s[SCAN_B];
    int t = threadIdx.x;
    int i = blockIdx.x * SCAN_B + t;
    int v = (i < n) ? cnt[i] : 0;
    s[t] = v;
    __syncthreads();
    for (int o = 1; o < SCAN_B; o <<= 1) {
        int a = (t >= o) ? s[t - o] : 0;
        __syncthreads();
        s[t] += a;
        __syncthreads();
    }
    if (i < n) rowptr[i] = s[t] - v;          // exclusive within block
    if (t == SCAN_B - 1) bsums[blockIdx.x] = s[t];
}

__global__ void k_scan2(int* bsums, int nb) {
    if (threadIdx.x == 0 && blockIdx.x == 0) {
        int run = 0;
        for (int b = 0; b < nb; ++b) { int v = bsums[b]; bsums[b] = run; run += v; }
    }
}

__global__ void k_scan3(int* rowptr, const int* __restrict__ bsums, int n, int etot) {
    int i = blockIdx.x * blockDim.x + threadIdx.x;
    if (i < n) rowptr[i] += bsums[i >> 10];
    else if (i == n) rowptr[n] = etot;
}

// scatter RAW weights, packed (src, w_bits) in one 8B store
__global__ void k_edge_scatter(const int* __restrict__ row, const int* __restrict__ col,
                               const float* __restrict__ w,
                               const int* __restrict__ rowptr, int* fill,
                               int2* __restrict__ csr, int e) {
    int i = blockIdx.x * blockDim.x + threadIdx.x;
    if (i < e) {
        int c = col[i];
        int pos = rowptr[c] + atomicAdd(&fill[c], 1);
        csr[pos] = make_int2(row[i], __float_as_int(w[i]));
    }
}

// deg[i] = 1 (self loop) + sum of raw weights into i; dinv = deg^-1/2
__global__ void k_deg(const int* __restrict__ rowptr, const int2* __restrict__ csr,
                      float* __restrict__ dinv, float* __restrict__ selfn, int n) {
    int i = blockIdx.x * blockDim.x + threadIdx.x;
    if (i >= n) return;
    int beg = rowptr[i], end = rowptr[i + 1];
    float d = 1.0f;
    for (int e = beg; e < end; ++e) d += __int_as_float(csr[e].y);
    float di = (d > 0.0f) ? (1.0f / sqrtf(d)) : 0.0f;
    dinv[i] = di;
    selfn[i] = di * di;
}

// csr_w[e] = dinv[src]*w*dinv[dst]; also s[i] = selfn[i] + sum(normalized w) = row-sum of A
__global__ void k_norm(const int* __restrict__ rowptr, int2* __restrict__ csr,
                       const float* __restrict__ dinv, const float* __restrict__ selfn,
                       float* __restrict__ s, int n) {
    int i = blockIdx.x * blockDim.x + threadIdx.x;
    if (i >= n) return;
    float dc = dinv[i];
    float acc = selfn[i];
    int beg = rowptr[i], end = rowptr[i + 1];
    for (int e = beg; e < end; ++e) {
        int2 v = csr[e];
        float nw = dinv[v.x] * __int_as_float(v.y) * dc;
        csr[e] = make_int2(v.x, __float_as_int(nw));
        acc += nw;
    }
    s[i] = acc;
}

// ---------------- fused weights: M = We@W1 [33x128], v = be@W1 [128] ----------------
__global__ void k_combine(const float* __restrict__ We, const float* __restrict__ W1,
                          const float* __restrict__ be,
                          float* __restrict__ M, float* __restrict__ v) {
    int f = threadIdx.x;            // 128
    int k = blockIdx.x;             // 0..33; 33 => bias row
    if (k < IN_DIM) {
        float a = 0.0f;
#pragma unroll 8
        for (int j = 0; j < HID; ++j) a += We[k * HID + j] * W1[j * HID + f];
        M[k * HID + f] = a;
    } else {
        float a = 0.0f;
#pragma unroll 8
        for (int j = 0; j < HID; ++j) a += be[j] * W1[j * HID + f];
        v[f] = a;
    }
}

// ---------------- Y = A @ x  (33-dim aggregate, incl self loop) ----------------
// round-5 cooperative form: 64 edge records loaded per wave, broadcast via shfl
__global__ __launch_bounds__(256) void k_agg_x(const float* __restrict__ x,
                                               const int* __restrict__ rowptr,
                                               const int2* __restrict__ csr,
                                               const float* __restrict__ selfn,
                                               float* __restrict__ Y, int n) {
    int i = (blockIdx.x * 256 + threadIdx.x) >> 6;
    if (i >= n) return;
    int lane = threadIdx.x & 63;
    float a = 0.0f;
    if (lane < IN_DIM) a = selfn[i] * x[szmul(i, IN_DIM) + lane];
    int beg = rowptr[i], end = rowptr[i + 1];
    for (int base = beg; base < end; base += 64) {
        int m = end - base; if (m > 64) m = 64;
        int2 e = make_int2(0, 0);
        if (lane < m) e = csr[base + lane];
#pragma unroll 2
        for (int j = 0; j < m; ++j) {
            int src = __shfl(e.x, j);
            float wj = __int_as_float(__shfl(e.y, j));
            if (lane < IN_DIM) a += wj * x[szmul(src, IN_DIM) + lane];
        }
    }
    if (lane < IN_DIM) Y[szmul(i, IN_DIM) + lane] = a;
}

// ---------------- h = relu(Y@M + s*v + b1)  (N x 33 @ 33 x 128) ----------------
__global__ __launch_bounds__(256) void k_gemm33(const float* __restrict__ Y,
                                                const float* __restrict__ M,
                                                const float* __restrict__ v,
                                                const float* __restrict__ s,
                                                const float* __restrict__ b1,
                                                float* __restrict__ h, int n) {
    __shared__ float sY[32 * IN_DIM];
    __shared__ float ss[32];
    int n0 = blockIdx.x * 32;
    int tid = threadIdx.x;
    int cnt = n - n0; if (cnt > 32) cnt = 32;
    for (int idx = tid; idx < cnt * IN_DIM; idx += 256)
        sY[idx] = Y[szmul(n0, IN_DIM) + idx];
    if (tid < cnt) ss[tid] = s[n0 + tid];
    __syncthreads();
    int f = tid & 127, g = tid >> 7;
    float Mc[IN_DIM];
#pragma unroll
    for (int k = 0; k < IN_DIM; ++k) Mc[k] = M[k * HID + f];
    float vf = v[f], bf = b1[f];
    int ndEnd = g * 16 + 16; if (ndEnd > cnt) ndEnd = cnt;
    for (int nd = g * 16; nd < ndEnd; ++nd) {
        float a = bf + ss[nd] * vf;
#pragma unroll
        for (int k = 0; k < IN_DIM; ++k) a += sY[nd * IN_DIM + k] * Mc[k];
        h[szmul(n0 + nd, HID) + f] = fmaxf(a, 0.0f);
    }
}

// ---------------- GEMM: T = A @ W  (A: n x 128 fp32, W: 128 x 128, T bf16) -------
__global__ __launch_bounds__(256) void k_gemm(const float* __restrict__ A,
                                              const float* __restrict__ W,
                                              unsigned short* __restrict__ Tb, int n) {
    __shared__ float sA[64][HID];   // 32 KiB
    int b0 = blockIdx.x * 64;
    int tid = threadIdx.x;
#pragma unroll
    for (int u = 0; u < 8; ++u) {
        int idx = u * 256 + tid;
        int r = idx >> 5, c4 = idx & 31;
        float4 v = make_float4(0.f, 0.f, 0.f, 0.f);
        if (b0 + r < n)
            v = *reinterpret_cast<const float4*>(A + szmul(b0 + r, HID) + c4 * 4);
        *reinterpret_cast<float4*>(&sA[r][c4 * 4]) = v;
    }
    __syncthreads();
    int ty = tid >> 5, tx = tid & 31;
    float acc0[8], acc1[8], acc2[8], acc3[8];
#pragma unroll
    for (int j = 0; j < 8; ++j) { acc0[j] = 0.f; acc1[j] = 0.f; acc2[j] = 0.f; acc3[j] = 0.f; }
    const float* Wp = W + tx * 4;
#pragma unroll 2
    for (int k = 0; k < HID; ++k) {
        float4 w4 = *reinterpret_cast<const float4*>(Wp + (size_t)k * HID);
#pragma unroll
        for (int j = 0; j < 8; ++j) {
            float a = sA[ty * 8 + j][k];
            acc0[j] += a * w4.x;
            acc1[j] += a * w4.y;
            acc2[j] += a * w4.z;
            acc3[j] += a * w4.w;
        }
    }
#pragma unroll
    for (int j = 0; j < 8; ++j) {
        int r = b0 + ty * 8 + j;
        if (r < n) {
            ushort4 o = make_ushort4(f2bf(acc0[j]), f2bf(acc1[j]),
                                     f2bf(acc2[j]), f2bf(acc3[j]));
            *reinterpret_cast<ushort4*>(&Tb[szmul(r, HID) + tx * 4]) = o;
        }
    }
}

// ---------------- aggregate: h[i] = relu(b + selfn[i]*t[i] + sum_e w_e * t[src_e]) ----
// bf16 messages: row = 256B, gathered as uint2 (8B) per lane over each half-wave.
// Wave per node; halves process edges j and j+1; fp32 accumulate; fp32 output.
__global__ __launch_bounds__(256) void k_aggregate(const uint2* __restrict__ tb,
                                                   const int* __restrict__ rowptr,
                                                   const int2* __restrict__ csr,
                                                   const float* __restrict__ selfn,
                                                   const float* __restrict__ bias,
                                                   float* __restrict__ hout, int n) {
    int i = (blockIdx.x * 256 + threadIdx.x) >> 6;
    if (i >= n) return;
    int lane = threadIdx.x & 63;
    int half = lane >> 5;
    int q = lane & 31;                        // uint2 index in row; features 4q..4q+3
    float a0 = 0.f, a1 = 0.f, a2 = 0.f, a3 = 0.f;
    if (half == 0) {
        uint2 sv = tb[szmul(i, 32) + q];
        float4 b4 = *reinterpret_cast<const float4*>(&bias[q * 4]);
        float sn = selfn[i];
        a0 = b4.x + sn * bf_lo(sv.x); a1 = b4.y + sn * bf_hi(sv.x);
        a2 = b4.z + sn * bf_lo(sv.y); a3 = b4.w + sn * bf_hi(sv.y);
    }
    int beg = rowptr[i], end = rowptr[i + 1];
    for (int base = beg; base < end; base += 64) {
        int m = end - base; if (m > 64) m = 64;
        int2 e = make_int2(0, 0);
        if (lane < m) e = csr[base + lane];
#pragma unroll 2
        for (int j = 0; j < m; j += 2) {
            int jj = j + half;                // lanes 0-31: edge j, 32-63: edge j+1
            int src = __shfl(e.x, jj);        // (0,0) beyond m -> w=0, contributes 0
            float wj = __int_as_float(__shfl(e.y, jj));
            uint2 r = tb[szmul(src, 32) + q];
            a0 += wj * bf_lo(r.x); a1 += wj * bf_hi(r.x);
            a2 += wj * bf_lo(r.y); a3 += wj * bf_hi(r.y);
        }
    }
    a0 += __shfl_xor(a0, 32); a1 += __shfl_xor(a1, 32);
    a2 += __shfl_xor(a2, 32); a3 += __shfl_xor(a3, 32);
    if (half == 0) {
        float4 o = make_float4(fmaxf(a0, 0.f), fmaxf(a1, 0.f),
                               fmaxf(a2, 0.f), fmaxf(a3, 0.f));
        *reinterpret_cast<float4*>(&hout[szmul(i, HID) + q * 4]) = o;
    }
}

// ---------------- pooling ----------------
__global__ void k_gcount_bs(const int* __restrict__ batch, int* gcnt, int n) {
    int g = threadIdx.x;
    if (g >= NG) return;
    int lo = 0, hi = n;
    while (lo < hi) { int mid = (lo + hi) >> 1; if (batch[mid] < g) lo = mid + 1; else hi = mid; }
    int start = lo;
    lo = 0; hi = n;
    while (lo < hi) { int mid = (lo + hi) >> 1; if (batch[mid] < g + 1) lo = mid + 1; else hi = mid; }
    gcnt[g] = lo - start;
}

__global__ __launch_bounds__(128) void k_pool(const float* __restrict__ h,
                                              const int* __restrict__ batch,
                                              float* gsum, int n) {
    int f = threadIdx.x;
    int i0 = blockIdx.x * 32;
    int i1 = min(i0 + 32, n);
    if (i0 >= n) return;
    float acc = 0.0f;
    int cur = batch[i0];
    for (int i = i0; i < i1; ++i) {
        int g = batch[i];
        if (g != cur) { atomicAdd(&gsum[cur * HID + f], acc); acc = 0.0f; cur = g; }
        acc += h[szmul(i, HID) + f];
    }
    atomicAdd(&gsum[cur * HID + f], acc);
}

// ---------------- readout MLP ----------------
__global__ __launch_bounds__(128) void k_mlp(const float* __restrict__ gsum,
                                             const int* __restrict__ gcnt,
                                             const float* __restrict__ Wr1, const float* __restrict__ br1,
                                             const float* __restrict__ Wr2, const float* __restrict__ br2,
                                             const float* __restrict__ Wr3,
                                             float* __restrict__ out) {
    int g = blockIdx.x;
    int t = threadIdx.x;
    __shared__ float p[HID];
    __shared__ float r1[64];
    __shared__ float r2[32];
    float c = fmaxf((float)gcnt[g], 1.0f);
    p[t] = gsum[g * HID + t] / c;
    __syncthreads();
    if (t < 64) {
        float a = br1[t];
#pragma unroll 8
        for (int k = 0; k < HID; ++k) a += p[k] * Wr1[k * 64 + t];
        r1[t] = fmaxf(a, 0.0f);
    }
    __syncthreads();
    if (t < 32) {
        float a = br2[t];
#pragma unroll 8
        for (int k = 0; k < 64; ++k) a += r1[k] * Wr2[k * 32 + t];
        r2[t] = fmaxf(a, 0.0f);
    }
    __syncthreads();
    if (t < NCLS) {
        float a = 0.0f;
#pragma unroll
        for (int k = 0; k < 32; ++k) a += r2[k] * Wr3[k * NCLS + t];
        out[g * NCLS + t] = a;
    }
}

extern "C" void kernel_launch(void* const* d_in, const int* in_sizes, int n_in,
                              void* d_out, int out_size, void* d_ws, size_t ws_size,
                              hipStream_t stream) {
    const float* x     = (const float*)d_in[0];
    const int*   ei    = (const int*)d_in[1];
    const float* ew    = (const float*)d_in[2];
    const int*   batch = (const int*)d_in[3];
    const float* We  = (const float*)d_in[4];
    const float* be  = (const float*)d_in[5];
    const float* Wl[4] = { (const float*)d_in[6], (const float*)d_in[8],
                           (const float*)d_in[10], (const float*)d_in[12] };
    const float* bl[4] = { (const float*)d_in[7], (const float*)d_in[9],
                           (const float*)d_in[11], (const float*)d_in[13] };
    const float* Wr1 = (const float*)d_in[14];
    const float* br1 = (const float*)d_in[15];
    const float* Wr2 = (const float*)d_in[16];
    const float* br2 = (const float*)d_in[17];
    const float* Wr3 = (const float*)d_in[18];
    float* out = (float*)d_out;

    const int N = in_sizes[3];      // 100000
    const int E = in_sizes[2];      // 1600000
    const int* row = ei;
    const int* col = ei + E;

    // workspace layout
    char* w = (char*)d_ws;
    size_t off = 0;
    auto alloc = [&](size_t bytes) -> void* {
        void* p = w + off;
        off = (off + bytes + 255) & ~(size_t)255;
        return p;
    };
    float* dinv    = (float*)alloc((size_t)N * 4);
    float* selfn   = (float*)alloc((size_t)N * 4);
    float* srow    = (float*)alloc((size_t)N * 4);       // row-sums of A
    int*   cnt     = (int*)  alloc((size_t)N * 4);
    int*   rowptr  = (int*)  alloc((size_t)(N + 1) * 4);
    int*   fill    = (int*)  alloc((size_t)N * 4);
    int*   bsums   = (int*)  alloc(4096);
    int2*  csr     = (int2*) alloc((size_t)E * 8);
    float* h       = (float*)alloc((size_t)N * HID * 4);
    unsigned short* tb = (unsigned short*)alloc((size_t)N * HID * 2);  // bf16 messages
    float* M       = (float*)alloc((size_t)IN_DIM * HID * 4);
    float* vbe     = (float*)alloc((size_t)HID * 4);
    float* gsum    = (float*)alloc((size_t)NG * HID * 4);
    int*   gcnt    = (int*)  alloc((size_t)NG * 4);
    float* Y       = (float*)tb;  // alias: Y[N][33] fp32 (13.2MB <= 25.6MB),
                                  // consumed by gemm33 before tb is first written
    (void)ws_size;

    auto cdiv = [](int a, int b) { return (a + b - 1) / b; };

    k_init<<<cdiv(N, 256), 256, 0, stream>>>(cnt, fill, gsum, N);
    k_edge_count<<<cdiv(E, 256), 256, 0, stream>>>(col, cnt, E);

    int nb = cdiv(N, SCAN_B);
    k_scan1<<<nb, SCAN_B, 0, stream>>>(cnt, rowptr, bsums, N);
    k_scan2<<<1, 64, 0, stream>>>(bsums, nb);
    k_scan3<<<cdiv(N + 1, 256), 256, 0, stream>>>(rowptr, bsums, N, E);
    k_edge_scatter<<<cdiv(E, 256), 256, 0, stream>>>(row, col, ew, rowptr, fill, csr, E);
    k_deg<<<cdiv(N, 256), 256, 0, stream>>>(rowptr, csr, dinv, selfn, N);
    k_norm<<<cdiv(N, 256), 256, 0, stream>>>(rowptr, csr, dinv, selfn, srow, N);

    // layer 1, restructured: h = relu((A x)(We W1) + s*(be W1) + b1)
    k_combine<<<IN_DIM + 1, HID, 0, stream>>>(We, Wl[0], be, M, vbe);
    k_agg_x<<<cdiv(N, 4), 256, 0, stream>>>(x, rowptr, csr, selfn, Y, N);
    k_gemm33<<<cdiv(N, 32), 256, 0, stream>>>(Y, M, vbe, srow, bl[0], h, N);

    // layers 2-4: bf16 messages
    for (int l = 1; l < 4; ++l) {
        k_gemm<<<cdiv(N, 64), 256, 0, stream>>>(h, Wl[l], tb, N);
        k_aggregate<<<cdiv(N, 4), 256, 0, stream>>>((const uint2*)tb, rowptr, csr,
                                                    selfn, bl[l], h, N);
    }

    k_gcount_bs<<<1, 128, 0, stream>>>(batch, gcnt, N);
    k_pool<<<cdiv(N, 32), 128, 0, stream>>>(h, batch, gsum, N);
    k_mlp<<<NG, HID, 0, stream>>>(gsum, gcnt, Wr1, br1, Wr2, br2, Wr3, out);

    (void)out_size; (void)n_in;
}

// Round 8
// 776.100 us; speedup vs baseline: 1.2336x; 1.0125x over previous
//
#include <hip/hip_runtime.h>
#include <hip/hip_bf16.h>

#define NN 100000
#define NE 1600000
#define IN_DIM 33
#define HID 128
#define NG 128
#define NCLS 10

static __device__ __forceinline__ size_t szmul(int a, int b) {
    return (size_t)a * (size_t)b;
}

// bf16 helpers: pack with RNE, unpack via bit ops (cheap: 1 VALU each)
static __device__ __forceinline__ unsigned short f2bf(float f) {
    unsigned u = __float_as_uint(f);
    u += 0x7fffu + ((u >> 16) & 1u);
    return (unsigned short)(u >> 16);
}
static __device__ __forceinline__ float bf_lo(unsigned u) { return __uint_as_float(u << 16); }
static __device__ __forceinline__ float bf_hi(unsigned u) { return __uint_as_float(u & 0xffff0000u); }

// ---------------- init ----------------
__global__ void k_init(int* cnt, int* fill, float* gsum, int n) {
    int i = blockIdx.x * blockDim.x + threadIdx.x;
    if (i < n) { cnt[i] = 0; fill[i] = 0; }
    if (i < NG * HID) gsum[i] = 0.0f;
}

// ---------------- CSR build ----------------
__global__ void k_edge_count(const int* __restrict__ col, int* cnt, int e) {
    int i = blockIdx.x * blockDim.x + threadIdx.x;
    if (i < e) atomicAdd(&cnt[col[i]], 1);
}

#define SCAN_B 1024
__global__ void k_scan1(const int* __restrict__ cnt, int* __restrict__ rowptr,
                        int* __restrict__ bsums, int n) {
    __shared__ int s[SCAN_B];
    int t = threadIdx.x;
    int i = blockIdx.x * SCAN_B + t;
    int v = (i < n) ? cnt[i] : 0;
    s[t] = v;
    __syncthreads();
    for (int o = 1; o < SCAN_B; o <<= 1) {
        int a = (t >= o) ? s[t - o] : 0;
        __syncthreads();
        s[t] += a;
        __syncthreads();
    }
    if (i < n) rowptr[i] = s[t] - v;          // exclusive within block
    if (t == SCAN_B - 1) bsums[blockIdx.x] = s[t];
}

__global__ void k_scan2(int* bsums, int nb) {
    if (threadIdx.x == 0 && blockIdx.x == 0) {
        int run = 0;
        for (int b = 0; b < nb; ++b) { int v = bsums[b]; bsums[b] = run; run += v; }
    }
}

__global__ void k_scan3(int* rowptr, const int* __restrict__ bsums, int n, int etot) {
    int i = blockIdx.x * blockDim.x + threadIdx.x;
    if (i < n) rowptr[i] += bsums[i >> 10];
    else if (i == n) rowptr[n] = etot;
}

// scatter RAW weights, packed (src, w_bits) in one 8B store
__global__ void k_edge_scatter(const int* __restrict__ row, const int* __restrict__ col,
                               const float* __restrict__ w,
                               const int* __restrict__ rowptr, int* fill,
                               int2* __restrict__ csr, int e) {
    int i = blockIdx.x * blockDim.x + threadIdx.x;
    if (i < e) {
        int c = col[i];
        int pos = rowptr[c] + atomicAdd(&fill[c], 1);
        csr[pos] = make_int2(row[i], __float_as_int(w[i]));
    }
}

// deg[i] = 1 (self loop) + sum of raw weights into i; dinv = deg^-1/2
__global__ void k_deg(const int* __restrict__ rowptr, const int2* __restrict__ csr,
                      float* __restrict__ dinv, float* __restrict__ selfn, int n) {
    int i = blockIdx.x * blockDim.x + threadIdx.x;
    if (i >= n) return;
    int beg = rowptr[i], end = rowptr[i + 1];
    float d = 1.0f;
    for (int e = beg; e < end; ++e) d += __int_as_float(csr[e].y);
    float di = (d > 0.0f) ? (1.0f / sqrtf(d)) : 0.0f;
    dinv[i] = di;
    selfn[i] = di * di;
}

// csr_w[e] = dinv[src]*w*dinv[dst]
__global__ void k_norm(const int* __restrict__ rowptr, int2* __restrict__ csr,
                       const float* __restrict__ dinv, int n) {
    int i = blockIdx.x * blockDim.x + threadIdx.x;
    if (i >= n) return;
    float dc = dinv[i];
    int beg = rowptr[i], end = rowptr[i + 1];
    for (int e = beg; e < end; ++e) {
        int2 v = csr[e];
        float nw = dinv[v.x] * __int_as_float(v.y) * dc;
        csr[e] = make_int2(v.x, __float_as_int(nw));
    }
}

// ---------------- fused weights: M = We@W1 [33x128], v = be@W1 [128] ----------------
__global__ void k_combine(const float* __restrict__ We, const float* __restrict__ W1,
                          const float* __restrict__ be,
                          float* __restrict__ M, float* __restrict__ v) {
    int f = threadIdx.x;            // 128
    int k = blockIdx.x;             // 0..33; 33 => bias row
    if (k < IN_DIM) {
        float a = 0.0f;
#pragma unroll 8
        for (int j = 0; j < HID; ++j) a += We[k * HID + j] * W1[j * HID + f];
        M[k * HID + f] = a;
    } else {
        float a = 0.0f;
#pragma unroll 8
        for (int j = 0; j < HID; ++j) a += be[j] * W1[j * HID + f];
        v[f] = a;
    }
}

// ---------------- t = bf16(x@M + v)  (N x 33 @ 33 x 128) ----------------
__global__ __launch_bounds__(256) void k_gemm_x(const float* __restrict__ x,
                                                const float* __restrict__ M,
                                                const float* __restrict__ v,
                                                unsigned short* __restrict__ tb, int n) {
    __shared__ float sX[32 * IN_DIM];
    int n0 = blockIdx.x * 32;
    int tid = threadIdx.x;
    int cnt = n - n0; if (cnt > 32) cnt = 32;
    for (int idx = tid; idx < cnt * IN_DIM; idx += 256)
        sX[idx] = x[szmul(n0, IN_DIM) + idx];
    __syncthreads();
    int f = tid & 127, g = tid >> 7;
    float Mc[IN_DIM];
#pragma unroll
    for (int k = 0; k < IN_DIM; ++k) Mc[k] = M[k * HID + f];
    float vf = v[f];
    int ndEnd = g * 16 + 16; if (ndEnd > cnt) ndEnd = cnt;
    for (int nd = g * 16; nd < ndEnd; ++nd) {
        float a = vf;
#pragma unroll
        for (int k = 0; k < IN_DIM; ++k) a += sX[nd * IN_DIM + k] * Mc[k];
        tb[szmul(n0 + nd, HID) + f] = f2bf(a);
    }
}

// ---------------- GEMM: T = A @ W  (A: n x 128 bf16-packed, W fp32, T bf16) -------
// A rows are 64 uints (2 bf16 each). LDS tile 64x64 uint = 16 KB.
__global__ __launch_bounds__(256) void k_gemm(const unsigned* __restrict__ A,
                                              const float* __restrict__ W,
                                              unsigned short* __restrict__ Tb, int n) {
    __shared__ unsigned sA[64][64];
    int b0 = blockIdx.x * 64;
    int tid = threadIdx.x;
#pragma unroll
    for (int u = 0; u < 4; ++u) {
        int idx = u * 256 + tid;
        int r = idx >> 4, c4 = idx & 15;      // 16 uint4 per row
        uint4 val = make_uint4(0, 0, 0, 0);
        if (b0 + r < n)
            val = *reinterpret_cast<const uint4*>(A + szmul(b0 + r, 64) + c4 * 4);
        *reinterpret_cast<uint4*>(&sA[r][c4 * 4]) = val;
    }
    __syncthreads();
    int ty = tid >> 5, tx = tid & 31;
    float acc0[8], acc1[8], acc2[8], acc3[8];
#pragma unroll
    for (int j = 0; j < 8; ++j) { acc0[j] = 0.f; acc1[j] = 0.f; acc2[j] = 0.f; acc3[j] = 0.f; }
    const float* Wp = W + tx * 4;
    for (int k2 = 0; k2 < 64; ++k2) {
        float4 we = *reinterpret_cast<const float4*>(Wp + (size_t)(2 * k2) * HID);
        float4 wo = *reinterpret_cast<const float4*>(Wp + (size_t)(2 * k2 + 1) * HID);
#pragma unroll
        for (int j = 0; j < 8; ++j) {
            unsigned p = sA[ty * 8 + j][k2];
            float ae = bf_lo(p), ao = bf_hi(p);
            acc0[j] += ae * we.x + ao * wo.x;
            acc1[j] += ae * we.y + ao * wo.y;
            acc2[j] += ae * we.z + ao * wo.z;
            acc3[j] += ae * we.w + ao * wo.w;
        }
    }
#pragma unroll
    for (int j = 0; j < 8; ++j) {
        int r = b0 + ty * 8 + j;
        if (r < n) {
            ushort4 o = make_ushort4(f2bf(acc0[j]), f2bf(acc1[j]),
                                     f2bf(acc2[j]), f2bf(acc3[j]));
            *reinterpret_cast<ushort4*>(&Tb[szmul(r, HID) + tx * 4]) = o;
        }
    }
}

// ---------------- aggregate: h[i] = relu(b + selfn[i]*t[i] + sum_e w_e * t[src_e]) ----
// bf16 in (256B rows, uint2/lane over half-wave), fp32 accum, bf16 out.
__global__ __launch_bounds__(256) void k_aggregate(const uint2* __restrict__ tb,
                                                   const int* __restrict__ rowptr,
                                                   const int2* __restrict__ csr,
                                                   const float* __restrict__ selfn,
                                                   const float* __restrict__ bias,
                                                   unsigned short* __restrict__ hout, int n) {
    int i = (blockIdx.x * 256 + threadIdx.x) >> 6;
    if (i >= n) return;
    int lane = threadIdx.x & 63;
    int half = lane >> 5;
    int q = lane & 31;                        // uint2 index in row; features 4q..4q+3
    float a0 = 0.f, a1 = 0.f, a2 = 0.f, a3 = 0.f;
    if (half == 0) {
        uint2 sv = tb[szmul(i, 32) + q];
        float4 b4 = *reinterpret_cast<const float4*>(&bias[q * 4]);
        float sn = selfn[i];
        a0 = b4.x + sn * bf_lo(sv.x); a1 = b4.y + sn * bf_hi(sv.x);
        a2 = b4.z + sn * bf_lo(sv.y); a3 = b4.w + sn * bf_hi(sv.y);
    }
    int beg = rowptr[i], end = rowptr[i + 1];
    for (int base = beg; base < end; base += 64) {
        int m = end - base; if (m > 64) m = 64;
        int2 e = make_int2(0, 0);
        if (lane < m) e = csr[base + lane];
#pragma unroll 2
        for (int j = 0; j < m; j += 2) {
            int jj = j + half;                // lanes 0-31: edge j, 32-63: edge j+1
            int src = __shfl(e.x, jj);        // (0,0) beyond m -> w=0, contributes 0
            float wj = __int_as_float(__shfl(e.y, jj));
            uint2 r = tb[szmul(src, 32) + q];
            a0 += wj * bf_lo(r.x); a1 += wj * bf_hi(r.x);
            a2 += wj * bf_lo(r.y); a3 += wj * bf_hi(r.y);
        }
    }
    a0 += __shfl_xor(a0, 32); a1 += __shfl_xor(a1, 32);
    a2 += __shfl_xor(a2, 32); a3 += __shfl_xor(a3, 32);
    if (half == 0) {
        ushort4 o = make_ushort4(f2bf(fmaxf(a0, 0.f)), f2bf(fmaxf(a1, 0.f)),
                                 f2bf(fmaxf(a2, 0.f)), f2bf(fmaxf(a3, 0.f)));
        *reinterpret_cast<ushort4*>(&hout[szmul(i, HID) + q * 4]) = o;
    }
}

// ---------------- pooling ----------------
__global__ void k_gcount_bs(const int* __restrict__ batch, int* gcnt, int n) {
    int g = threadIdx.x;
    if (g >= NG) return;
    int lo = 0, hi = n;
    while (lo < hi) { int mid = (lo + hi) >> 1; if (batch[mid] < g) lo = mid + 1; else hi = mid; }
    int start = lo;
    lo = 0; hi = n;
    while (lo < hi) { int mid = (lo + hi) >> 1; if (batch[mid] < g + 1) lo = mid + 1; else hi = mid; }
    gcnt[g] = lo - start;
}

__global__ __launch_bounds__(128) void k_pool(const unsigned short* __restrict__ h,
                                              const int* __restrict__ batch,
                                              float* gsum, int n) {
    int f = threadIdx.x;
    int i0 = blockIdx.x * 32;
    int i1 = min(i0 + 32, n);
    if (i0 >= n) return;
    float acc = 0.0f;
    int cur = batch[i0];
    for (int i = i0; i < i1; ++i) {
        int g = batch[i];
        if (g != cur) { atomicAdd(&gsum[cur * HID + f], acc); acc = 0.0f; cur = g; }
        acc += __uint_as_float((unsigned)h[szmul(i, HID) + f] << 16);
    }
    atomicAdd(&gsum[cur * HID + f], acc);
}

// ---------------- readout MLP ----------------
__global__ __launch_bounds__(128) void k_mlp(const float* __restrict__ gsum,
                                             const int* __restrict__ gcnt,
                                             const float* __restrict__ Wr1, const float* __restrict__ br1,
                                             const float* __restrict__ Wr2, const float* __restrict__ br2,
                                             const float* __restrict__ Wr3,
                                             float* __restrict__ out) {
    int g = blockIdx.x;
    int t = threadIdx.x;
    __shared__ float p[HID];
    __shared__ float r1[64];
    __shared__ float r2[32];
    float c = fmaxf((float)gcnt[g], 1.0f);
    p[t] = gsum[g * HID + t] / c;
    __syncthreads();
    if (t < 64) {
        float a = br1[t];
#pragma unroll 8
        for (int k = 0; k < HID; ++k) a += p[k] * Wr1[k * 64 + t];
        r1[t] = fmaxf(a, 0.0f);
    }
    __syncthreads();
    if (t < 32) {
        float a = br2[t];
#pragma unroll 8
        for (int k = 0; k < 64; ++k) a += r1[k] * Wr2[k * 32 + t];
        r2[t] = fmaxf(a, 0.0f);
    }
    __syncthreads();
    if (t < NCLS) {
        float a = 0.0f;
#pragma unroll
        for (int k = 0; k < 32; ++k) a += r2[k] * Wr3[k * NCLS + t];
        out[g * NCLS + t] = a;
    }
}

extern "C" void kernel_launch(void* const* d_in, const int* in_sizes, int n_in,
                              void* d_out, int out_size, void* d_ws, size_t ws_size,
                              hipStream_t stream) {
    const float* x     = (const float*)d_in[0];
    const int*   ei    = (const int*)d_in[1];
    const float* ew    = (const float*)d_in[2];
    const int*   batch = (const int*)d_in[3];
    const float* We  = (const float*)d_in[4];
    const float* be  = (const float*)d_in[5];
    const float* Wl[4] = { (const float*)d_in[6], (const float*)d_in[8],
                           (const float*)d_in[10], (const float*)d_in[12] };
    const float* bl[4] = { (const float*)d_in[7], (const float*)d_in[9],
                           (const float*)d_in[11], (const float*)d_in[13] };
    const float* Wr1 = (const float*)d_in[14];
    const float* br1 = (const float*)d_in[15];
    const float* Wr2 = (const float*)d_in[16];
    const float* br2 = (const float*)d_in[17];
    const float* Wr3 = (const float*)d_in[18];
    float* out = (float*)d_out;

    const int N = in_sizes[3];      // 100000
    const int E = in_sizes[2];      // 1600000
    const int* row = ei;
    const int* col = ei + E;

    // workspace layout
    char* w = (char*)d_ws;
    size_t off = 0;
    auto alloc = [&](size_t bytes) -> void* {
        void* p = w + off;
        off = (off + bytes + 255) & ~(size_t)255;
        return p;
    };
    float* dinv    = (float*)alloc((size_t)N * 4);
    float* selfn   = (float*)alloc((size_t)N * 4);
    int*   cnt     = (int*)  alloc((size_t)N * 4);
    int*   rowptr  = (int*)  alloc((size_t)(N + 1) * 4);
    int*   fill    = (int*)  alloc((size_t)N * 4);
    int*   bsums   = (int*)  alloc(4096);
    int2*  csr     = (int2*) alloc((size_t)E * 8);
    unsigned short* h  = (unsigned short*)alloc((size_t)N * HID * 2);  // bf16 activations
    unsigned short* tb = (unsigned short*)alloc((size_t)N * HID * 2);  // bf16 messages
    float* M       = (float*)alloc((size_t)IN_DIM * HID * 4);
    float* vbe     = (float*)alloc((size_t)HID * 4);
    float* gsum    = (float*)alloc((size_t)NG * HID * 4);
    int*   gcnt    = (int*)  alloc((size_t)NG * 4);
    (void)ws_size;

    auto cdiv = [](int a, int b) { return (a + b - 1) / b; };

    k_init<<<cdiv(N, 256), 256, 0, stream>>>(cnt, fill, gsum, N);
    k_edge_count<<<cdiv(E, 256), 256, 0, stream>>>(col, cnt, E);

    int nb = cdiv(N, SCAN_B);
    k_scan1<<<nb, SCAN_B, 0, stream>>>(cnt, rowptr, bsums, N);
    k_scan2<<<1, 64, 0, stream>>>(bsums, nb);
    k_scan3<<<cdiv(N + 1, 256), 256, 0, stream>>>(rowptr, bsums, N, E);
    k_edge_scatter<<<cdiv(E, 256), 256, 0, stream>>>(row, col, ew, rowptr, fill, csr, E);
    k_deg<<<cdiv(N, 256), 256, 0, stream>>>(rowptr, csr, dinv, selfn, N);
    k_norm<<<cdiv(N, 256), 256, 0, stream>>>(rowptr, csr, dinv, N);

    // layer 1: t = bf16(x@(We@W1) + be@W1); h = relu(agg(t) + b1)
    k_combine<<<IN_DIM + 1, HID, 0, stream>>>(We, Wl[0], be, M, vbe);
    k_gemm_x<<<cdiv(N, 32), 256, 0, stream>>>(x, M, vbe, tb, N);
    k_aggregate<<<cdiv(N, 4), 256, 0, stream>>>((const uint2*)tb, rowptr, csr,
                                                selfn, bl[0], h, N);

    // layers 2-4: bf16 GEMM + bf16 aggregate
    for (int l = 1; l < 4; ++l) {
        k_gemm<<<cdiv(N, 64), 256, 0, stream>>>((const unsigned*)h, Wl[l], tb, N);
        k_aggregate<<<cdiv(N, 4), 256, 0, stream>>>((const uint2*)tb, rowptr, csr,
                                                    selfn, bl[l], h, N);
    }

    k_gcount_bs<<<1, 128, 0, stream>>>(batch, gcnt, N);
    k_pool<<<cdiv(N, 32), 128, 0, stream>>>(h, batch, gsum, N);
    k_mlp<<<NG, HID, 0, stream>>>(gsum, gcnt, Wr1, br1, Wr2, br2, Wr3, out);

    (void)out_size; (void)n_in;
}

// Round 9
// 672.131 us; speedup vs baseline: 1.4244x; 1.1547x over previous
//
#include <hip/hip_runtime.h>
#include <hip/hip_bf16.h>

#define NN 100000
#define NE 1600000
#define IN_DIM 33
#define HID 128
#define NG 128
#define NCLS 10

static __device__ __forceinline__ size_t szmul(int a, int b) {
    return (size_t)a * (size_t)b;
}

// bf16 helpers: pack with RNE, unpack via bit ops (cheap: 1 VALU each)
static __device__ __forceinline__ unsigned short f2bf(float f) {
    unsigned u = __float_as_uint(f);
    u += 0x7fffu + ((u >> 16) & 1u);
    return (unsigned short)(u >> 16);
}
static __device__ __forceinline__ float bf_lo(unsigned u) { return __uint_as_float(u << 16); }
static __device__ __forceinline__ float bf_hi(unsigned u) { return __uint_as_float(u & 0xffff0000u); }

// ---------------- init ----------------
__global__ void k_init(int* bucket_cnt, int* bucket_fill, float* gsum) {
    int i = blockIdx.x * blockDim.x + threadIdx.x;
    if (i < 513) { bucket_cnt[i] = 0; bucket_fill[i] = 0; }
    if (i < NG * HID) gsum[i] = 0.0f;
}

// ---------------- binned CSR build ----------------
// bucket = col >> 8 (256 nodes per bucket, nbk = ceil(N/256) = 391)

// Pass A: bucket histogram, LDS-aggregated
__global__ __launch_bounds__(256) void k_bhist(const int* __restrict__ col,
                                               int* __restrict__ bucket_cnt, int e, int nbk) {
    __shared__ int hist[512];
    int tid = threadIdx.x;
    for (int i = tid; i < nbk; i += 256) hist[i] = 0;
    __syncthreads();
    for (int i = blockIdx.x * 256 + tid; i < e; i += 256 * 256)
        atomicAdd(&hist[col[i] >> 8], 1);
    __syncthreads();
    for (int i = tid; i < nbk; i += 256)
        if (hist[i]) atomicAdd(&bucket_cnt[i], hist[i]);
}

// parallel exclusive scan over nb <= 512 elements, in place; data[nb] = total
__global__ void k_scan_small(int* data, int nb) {
    __shared__ int s[512];
    int t = threadIdx.x;
    int v = (t < nb) ? data[t] : 0;
    s[t] = v;
    __syncthreads();
    for (int o = 1; o < 512; o <<= 1) {
        int a = (t >= o) ? s[t - o] : 0;
        __syncthreads();
        s[t] += a;
        __syncthreads();
    }
    if (t < nb) data[t] = s[t] - v;
    if (t == nb - 1) data[nb] = s[t];
}

// Pass C: binned scatter. Each block multisplits 2048 edges by bucket in LDS,
// reserves global space per touched bucket, writes records grouped by bucket.
// Record: x = (col&255)<<17 | src (src < 2^17), y = raw w bits.
__global__ __launch_bounds__(256) void k_bin_scatter(const int* __restrict__ row,
                                                     const int* __restrict__ col,
                                                     const float* __restrict__ w,
                                                     const int* __restrict__ bucket_base,
                                                     int* __restrict__ bucket_fill,
                                                     uint2* __restrict__ binned, int e, int nbk) {
    __shared__ int hist[512], rnk[512], basub[512];
    int tid = threadIdx.x;
    int c0 = blockIdx.x * 2048;
    for (int i = tid; i < nbk; i += 256) { hist[i] = 0; rnk[i] = 0; }
    __syncthreads();
    int myb[8]; unsigned myp[8]; unsigned myw[8];
#pragma unroll
    for (int u = 0; u < 8; ++u) {
        int idx = c0 + u * 256 + tid;
        int b = -1;
        if (idx < e) {
            int c = col[idx];
            int r = row[idx];
            myw[u] = __float_as_uint(w[idx]);
            b = c >> 8;
            myp[u] = ((unsigned)(c & 255) << 17) | (unsigned)r;
            atomicAdd(&hist[b], 1);
        }
        myb[u] = b;
    }
    __syncthreads();
    for (int i = tid; i < nbk; i += 256) {
        int c = hist[i];
        basub[i] = (c > 0) ? (bucket_base[i] + atomicAdd(&bucket_fill[i], c)) : 0;
    }
    __syncthreads();
#pragma unroll
    for (int u = 0; u < 8; ++u) {
        int b = myb[u];
        if (b >= 0) {
            int rk = atomicAdd(&rnk[b], 1);
            binned[basub[b] + rk] = make_uint2(myp[u], myw[u]);
        }
    }
}

// Pass D1: per-bucket node histogram -> cnt (no global atomics)
__global__ __launch_bounds__(256) void k_bucket_cnt(const uint2* __restrict__ binned,
                                                    const int* __restrict__ bucket_base,
                                                    int* __restrict__ cnt, int n) {
    __shared__ int c256[256];
    int b = blockIdx.x, tid = threadIdx.x;
    c256[tid] = 0;
    __syncthreads();
    int beg = bucket_base[b], end = bucket_base[b + 1];
    for (int e2 = beg + tid; e2 < end; e2 += 256)
        atomicAdd(&c256[(binned[e2].x >> 17) & 255], 1);
    __syncthreads();
    int node = b * 256 + tid;
    if (node < n) cnt[node] = c256[tid];
}

#define SCAN_B 1024
__global__ void k_scan1(const int* __restrict__ cnt, int* __restrict__ rowptr,
                        int* __restrict__ bsums, int n) {
    __shared__ int s[SCAN_B];
    int t = threadIdx.x;
    int i = blockIdx.x * SCAN_B + t;
    int v = (i < n) ? cnt[i] : 0;
    s[t] = v;
    __syncthreads();
    for (int o = 1; o < SCAN_B; o <<= 1) {
        int a = (t >= o) ? s[t - o] : 0;
        __syncthreads();
        s[t] += a;
        __syncthreads();
    }
    if (i < n) rowptr[i] = s[t] - v;          // exclusive within block
    if (t == SCAN_B - 1) bsums[blockIdx.x] = s[t];
}

__global__ void k_scan3(int* rowptr, const int* __restrict__ bsums, int n, int etot) {
    int i = blockIdx.x * blockDim.x + threadIdx.x;
    if (i < n) rowptr[i] += bsums[i >> 10];
    else if (i == n) rowptr[n] = etot;
}

// Pass D2: per-bucket final scatter; writes land within the bucket's ~32KB
// CSR extent -> L2-absorbed, full lines to HBM.
__global__ __launch_bounds__(256) void k_bucket_scatter(const uint2* __restrict__ binned,
                                                        const int* __restrict__ bucket_base,
                                                        const int* __restrict__ rowptr,
                                                        int2* __restrict__ csr, int n) {
    __shared__ int f256[256];
    int b = blockIdx.x, tid = threadIdx.x;
    f256[tid] = 0;
    __syncthreads();
    int beg = bucket_base[b], end = bucket_base[b + 1];
    for (int e2 = beg + tid; e2 < end; e2 += 256) {
        uint2 rec = binned[e2];
        int lo = (rec.x >> 17) & 255;
        int node = (b << 8) | lo;
        int src = rec.x & 0x1FFFF;
        int pos = rowptr[node] + atomicAdd(&f256[lo], 1);
        csr[pos] = make_int2(src, (int)rec.y);
    }
    (void)n;
}

// deg[i] = 1 (self loop) + sum of raw weights into i; dinv = deg^-1/2
__global__ void k_deg(const int* __restrict__ rowptr, const int2* __restrict__ csr,
                      float* __restrict__ dinv, float* __restrict__ selfn, int n) {
    int i = blockIdx.x * blockDim.x + threadIdx.x;
    if (i >= n) return;
    int beg = rowptr[i], end = rowptr[i + 1];
    float d = 1.0f;
    for (int e = beg; e < end; ++e) d += __int_as_float(csr[e].y);
    float di = (d > 0.0f) ? (1.0f / sqrtf(d)) : 0.0f;
    dinv[i] = di;
    selfn[i] = di * di;
}

// csr_w[e] = dinv[src]*w*dinv[dst]
__global__ void k_norm(const int* __restrict__ rowptr, int2* __restrict__ csr,
                       const float* __restrict__ dinv, int n) {
    int i = blockIdx.x * blockDim.x + threadIdx.x;
    if (i >= n) return;
    float dc = dinv[i];
    int beg = rowptr[i], end = rowptr[i + 1];
    for (int e = beg; e < end; ++e) {
        int2 v = csr[e];
        float nw = dinv[v.x] * __int_as_float(v.y) * dc;
        csr[e] = make_int2(v.x, __float_as_int(nw));
    }
}

// ---------------- fused weights: M = We@W1 [33x128], v = be@W1 [128] ----------------
__global__ void k_combine(const float* __restrict__ We, const float* __restrict__ W1,
                          const float* __restrict__ be,
                          float* __restrict__ M, float* __restrict__ v) {
    int f = threadIdx.x;            // 128
    int k = blockIdx.x;             // 0..33; 33 => bias row
    if (k < IN_DIM) {
        float a = 0.0f;
#pragma unroll 8
        for (int j = 0; j < HID; ++j) a += We[k * HID + j] * W1[j * HID + f];
        M[k * HID + f] = a;
    } else {
        float a = 0.0f;
#pragma unroll 8
        for (int j = 0; j < HID; ++j) a += be[j] * W1[j * HID + f];
        v[f] = a;
    }
}

// ---------------- t = bf16(x@M + v)  (N x 33 @ 33 x 128) ----------------
__global__ __launch_bounds__(256) void k_gemm_x(const float* __restrict__ x,
                                                const float* __restrict__ M,
                                                const float* __restrict__ v,
                                                unsigned short* __restrict__ tb, int n) {
    __shared__ float sX[32 * IN_DIM];
    int n0 = blockIdx.x * 32;
    int tid = threadIdx.x;
    int cnt = n - n0; if (cnt > 32) cnt = 32;
    for (int idx = tid; idx < cnt * IN_DIM; idx += 256)
        sX[idx] = x[szmul(n0, IN_DIM) + idx];
    __syncthreads();
    int f = tid & 127, g = tid >> 7;
    float Mc[IN_DIM];
#pragma unroll
    for (int k = 0; k < IN_DIM; ++k) Mc[k] = M[k * HID + f];
    float vf = v[f];
    int ndEnd = g * 16 + 16; if (ndEnd > cnt) ndEnd = cnt;
    for (int nd = g * 16; nd < ndEnd; ++nd) {
        float a = vf;
#pragma unroll
        for (int k = 0; k < IN_DIM; ++k) a += sX[nd * IN_DIM + k] * Mc[k];
        tb[szmul(n0 + nd, HID) + f] = f2bf(a);
    }
}

// ---------------- GEMM: T = A @ W  (A: n x 128 bf16-packed, W fp32, T bf16) -------
__global__ __launch_bounds__(256) void k_gemm(const unsigned* __restrict__ A,
                                              const float* __restrict__ W,
                                              unsigned short* __restrict__ Tb, int n) {
    __shared__ unsigned sA[64][64];
    int b0 = blockIdx.x * 64;
    int tid = threadIdx.x;
#pragma unroll
    for (int u = 0; u < 4; ++u) {
        int idx = u * 256 + tid;
        int r = idx >> 4, c4 = idx & 15;      // 16 uint4 per row
        uint4 val = make_uint4(0, 0, 0, 0);
        if (b0 + r < n)
            val = *reinterpret_cast<const uint4*>(A + szmul(b0 + r, 64) + c4 * 4);
        *reinterpret_cast<uint4*>(&sA[r][c4 * 4]) = val;
    }
    __syncthreads();
    int ty = tid >> 5, tx = tid & 31;
    float acc0[8], acc1[8], acc2[8], acc3[8];
#pragma unroll
    for (int j = 0; j < 8; ++j) { acc0[j] = 0.f; acc1[j] = 0.f; acc2[j] = 0.f; acc3[j] = 0.f; }
    const float* Wp = W + tx * 4;
    for (int k2 = 0; k2 < 64; ++k2) {
        float4 we = *reinterpret_cast<const float4*>(Wp + (size_t)(2 * k2) * HID);
        float4 wo = *reinterpret_cast<const float4*>(Wp + (size_t)(2 * k2 + 1) * HID);
#pragma unroll
        for (int j = 0; j < 8; ++j) {
            unsigned p = sA[ty * 8 + j][k2];
            float ae = bf_lo(p), ao = bf_hi(p);
            acc0[j] += ae * we.x + ao * wo.x;
            acc1[j] += ae * we.y + ao * wo.y;
            acc2[j] += ae * we.z + ao * wo.z;
            acc3[j] += ae * we.w + ao * wo.w;
        }
    }
#pragma unroll
    for (int j = 0; j < 8; ++j) {
        int r = b0 + ty * 8 + j;
        if (r < n) {
            ushort4 o = make_ushort4(f2bf(acc0[j]), f2bf(acc1[j]),
                                     f2bf(acc2[j]), f2bf(acc3[j]));
            *reinterpret_cast<ushort4*>(&Tb[szmul(r, HID) + tx * 4]) = o;
        }
    }
}

// ---------------- aggregate: h[i] = relu(b + selfn[i]*t[i] + sum_e w_e * t[src_e]) ----
__global__ __launch_bounds__(256) void k_aggregate(const uint2* __restrict__ tb,
                                                   const int* __restrict__ rowptr,
                                                   const int2* __restrict__ csr,
                                                   const float* __restrict__ selfn,
                                                   const float* __restrict__ bias,
                                                   unsigned short* __restrict__ hout, int n) {
    int i = (blockIdx.x * 256 + threadIdx.x) >> 6;
    if (i >= n) return;
    int lane = threadIdx.x & 63;
    int half = lane >> 5;
    int q = lane & 31;                        // uint2 index in row; features 4q..4q+3
    float a0 = 0.f, a1 = 0.f, a2 = 0.f, a3 = 0.f;
    if (half == 0) {
        uint2 sv = tb[szmul(i, 32) + q];
        float4 b4 = *reinterpret_cast<const float4*>(&bias[q * 4]);
        float sn = selfn[i];
        a0 = b4.x + sn * bf_lo(sv.x); a1 = b4.y + sn * bf_hi(sv.x);
        a2 = b4.z + sn * bf_lo(sv.y); a3 = b4.w + sn * bf_hi(sv.y);
    }
    int beg = rowptr[i], end = rowptr[i + 1];
    for (int base = beg; base < end; base += 64) {
        int m = end - base; if (m > 64) m = 64;
        int2 e = make_int2(0, 0);
        if (lane < m) e = csr[base + lane];
#pragma unroll 2
        for (int j = 0; j < m; j += 2) {
            int jj = j + half;                // lanes 0-31: edge j, 32-63: edge j+1
            int src = __shfl(e.x, jj);        // (0,0) beyond m -> w=0, contributes 0
            float wj = __int_as_float(__shfl(e.y, jj));
            uint2 r = tb[szmul(src, 32) + q];
            a0 += wj * bf_lo(r.x); a1 += wj * bf_hi(r.x);
            a2 += wj * bf_lo(r.y); a3 += wj * bf_hi(r.y);
        }
    }
    a0 += __shfl_xor(a0, 32); a1 += __shfl_xor(a1, 32);
    a2 += __shfl_xor(a2, 32); a3 += __shfl_xor(a3, 32);
    if (half == 0) {
        ushort4 o = make_ushort4(f2bf(fmaxf(a0, 0.f)), f2bf(fmaxf(a1, 0.f)),
                                 f2bf(fmaxf(a2, 0.f)), f2bf(fmaxf(a3, 0.f)));
        *reinterpret_cast<ushort4*>(&hout[szmul(i, HID) + q * 4]) = o;
    }
}

// ---------------- pooling ----------------
__global__ void k_gcount_bs(const int* __restrict__ batch, int* gcnt, int n) {
    int g = threadIdx.x;
    if (g >= NG) return;
    int lo = 0, hi = n;
    while (lo < hi) { int mid = (lo + hi) >> 1; if (batch[mid] < g) lo = mid + 1; else hi = mid; }
    int start = lo;
    lo = 0; hi = n;
    while (lo < hi) { int mid = (lo + hi) >> 1; if (batch[mid] < g + 1) lo = mid + 1; else hi = mid; }
    gcnt[g] = lo - start;
}

__global__ __launch_bounds__(128) void k_pool(const unsigned short* __restrict__ h,
                                              const int* __restrict__ batch,
                                              float* gsum, int n) {
    int f = threadIdx.x;
    int i0 = blockIdx.x * 32;
    int i1 = min(i0 + 32, n);
    if (i0 >= n) return;
    float acc = 0.0f;
    int cur = batch[i0];
    for (int i = i0; i < i1; ++i) {
        int g = batch[i];
        if (g != cur) { atomicAdd(&gsum[cur * HID + f], acc); acc = 0.0f; cur = g; }
        acc += __uint_as_float((unsigned)h[szmul(i, HID) + f] << 16);
    }
    atomicAdd(&gsum[cur * HID + f], acc);
}

// ---------------- readout MLP ----------------
__global__ __launch_bounds__(128) void k_mlp(const float* __restrict__ gsum,
                                             const int* __restrict__ gcnt,
                                             const float* __restrict__ Wr1, const float* __restrict__ br1,
                                             const float* __restrict__ Wr2, const float* __restrict__ br2,
                                             const float* __restrict__ Wr3,
                                             float* __restrict__ out) {
    int g = blockIdx.x;
    int t = threadIdx.x;
    __shared__ float p[HID];
    __shared__ float r1[64];
    __shared__ float r2[32];
    float c = fmaxf((float)gcnt[g], 1.0f);
    p[t] = gsum[g * HID + t] / c;
    __syncthreads();
    if (t < 64) {
        float a = br1[t];
#pragma unroll 8
        for (int k = 0; k < HID; ++k) a += p[k] * Wr1[k * 64 + t];
        r1[t] = fmaxf(a, 0.0f);
    }
    __syncthreads();
    if (t < 32) {
        float a = br2[t];
#pragma unroll 8
        for (int k = 0; k < 64; ++k) a += r1[k] * Wr2[k * 32 + t];
        r2[t] = fmaxf(a, 0.0f);
    }
    __syncthreads();
    if (t < NCLS) {
        float a = 0.0f;
#pragma unroll
        for (int k = 0; k < 32; ++k) a += r2[k] * Wr3[k * NCLS + t];
        out[g * NCLS + t] = a;
    }
}

extern "C" void kernel_launch(void* const* d_in, const int* in_sizes, int n_in,
                              void* d_out, int out_size, void* d_ws, size_t ws_size,
                              hipStream_t stream) {
    const float* x     = (const float*)d_in[0];
    const int*   ei    = (const int*)d_in[1];
    const float* ew    = (const float*)d_in[2];
    const int*   batch = (const int*)d_in[3];
    const float* We  = (const float*)d_in[4];
    const float* be  = (const float*)d_in[5];
    const float* Wl[4] = { (const float*)d_in[6], (const float*)d_in[8],
                           (const float*)d_in[10], (const float*)d_in[12] };
    const float* bl[4] = { (const float*)d_in[7], (const float*)d_in[9],
                           (const float*)d_in[11], (const float*)d_in[13] };
    const float* Wr1 = (const float*)d_in[14];
    const float* br1 = (const float*)d_in[15];
    const float* Wr2 = (const float*)d_in[16];
    const float* br2 = (const float*)d_in[17];
    const float* Wr3 = (const float*)d_in[18];
    float* out = (float*)d_out;

    const int N = in_sizes[3];      // 100000
    const int E = in_sizes[2];      // 1600000
    const int* row = ei;
    const int* col = ei + E;
    const int nbk = (N + 255) >> 8; // 391 buckets

    // workspace layout
    char* w = (char*)d_ws;
    size_t off = 0;
    auto alloc = [&](size_t bytes) -> void* {
        void* p = w + off;
        off = (off + bytes + 255) & ~(size_t)255;
        return p;
    };
    float* dinv       = (float*)alloc((size_t)N * 4);
    float* selfn      = (float*)alloc((size_t)N * 4);
    int*   cnt        = (int*)  alloc((size_t)N * 4);
    int*   rowptr     = (int*)  alloc((size_t)(N + 1) * 4);
    int*   bsums      = (int*)  alloc(4096);
    int*   bucket_cnt = (int*)  alloc(513 * 4);   // becomes bucket_base after scan
    int*   bucket_fill= (int*)  alloc(513 * 4);
    int2*  csr        = (int2*) alloc((size_t)E * 8);
    unsigned short* h  = (unsigned short*)alloc((size_t)N * HID * 2);  // bf16 activations
    unsigned short* tb = (unsigned short*)alloc((size_t)N * HID * 2);  // bf16 messages
    float* M          = (float*)alloc((size_t)IN_DIM * HID * 4);
    float* vbe        = (float*)alloc((size_t)HID * 4);
    float* gsum       = (float*)alloc((size_t)NG * HID * 4);
    int*   gcnt       = (int*)  alloc((size_t)NG * 4);
    uint2* binned     = (uint2*)tb;  // alias: consumed by D1/D2 before tb first written
    (void)ws_size;

    auto cdiv = [](int a, int b) { return (a + b - 1) / b; };

    // ---- binned CSR build ----
    k_init<<<64, 256, 0, stream>>>(bucket_cnt, bucket_fill, gsum);
    k_bhist<<<256, 256, 0, stream>>>(col, bucket_cnt, E, nbk);
    k_scan_small<<<1, 512, 0, stream>>>(bucket_cnt, nbk);        // -> bucket_base
    k_bin_scatter<<<cdiv(E, 2048), 256, 0, stream>>>(row, col, ew, bucket_cnt,
                                                     bucket_fill, binned, E, nbk);
    k_bucket_cnt<<<nbk, 256, 0, stream>>>(binned, bucket_cnt, cnt, N);

    int nb = cdiv(N, SCAN_B);
    k_scan1<<<nb, SCAN_B, 0, stream>>>(cnt, rowptr, bsums, N);
    k_scan_small<<<1, 512, 0, stream>>>(bsums, nb);
    k_scan3<<<cdiv(N + 1, 256), 256, 0, stream>>>(rowptr, bsums, N, E);
    k_bucket_scatter<<<nbk, 256, 0, stream>>>(binned, bucket_cnt, rowptr, csr, N);

    k_deg<<<cdiv(N, 256), 256, 0, stream>>>(rowptr, csr, dinv, selfn, N);
    k_norm<<<cdiv(N, 256), 256, 0, stream>>>(rowptr, csr, dinv, N);

    // layer 1: t = bf16(x@(We@W1) + be@W1); h = relu(agg(t) + b1)
    k_combine<<<IN_DIM + 1, HID, 0, stream>>>(We, Wl[0], be, M, vbe);
    k_gemm_x<<<cdiv(N, 32), 256, 0, stream>>>(x, M, vbe, tb, N);
    k_aggregate<<<cdiv(N, 4), 256, 0, stream>>>((const uint2*)tb, rowptr, csr,
                                                selfn, bl[0], h, N);

    // layers 2-4: bf16 GEMM + bf16 aggregate
    for (int l = 1; l < 4; ++l) {
        k_gemm<<<cdiv(N, 64), 256, 0, stream>>>((const unsigned*)h, Wl[l], tb, N);
        k_aggregate<<<cdiv(N, 4), 256, 0, stream>>>((const uint2*)tb, rowptr, csr,
                                                    selfn, bl[l], h, N);
    }

    k_gcount_bs<<<1, 128, 0, stream>>>(batch, gcnt, N);
    k_pool<<<cdiv(N, 32), 128, 0, stream>>>(h, batch, gsum, N);
    k_mlp<<<NG, HID, 0, stream>>>(gsum, gcnt, Wr1, br1, Wr2, br2, Wr3, out);

    (void)out_size; (void)n_in;
}

// Round 10
// 629.642 us; speedup vs baseline: 1.5206x; 1.0675x over previous
//
#include <hip/hip_runtime.h>
#include <hip/hip_bf16.h>

#define NN 100000
#define NE 1600000
#define IN_DIM 33
#define HID 128
#define NG 128
#define NCLS 10

static __device__ __forceinline__ size_t szmul(int a, int b) {
    return (size_t)a * (size_t)b;
}

// bf16 helpers: pack with RNE, unpack via bit ops (cheap: 1 VALU each)
static __device__ __forceinline__ unsigned short f2bf(float f) {
    unsigned u = __float_as_uint(f);
    u += 0x7fffu + ((u >> 16) & 1u);
    return (unsigned short)(u >> 16);
}
static __device__ __forceinline__ float bf_lo(unsigned u) { return __uint_as_float(u << 16); }
static __device__ __forceinline__ float bf_hi(unsigned u) { return __uint_as_float(u & 0xffff0000u); }

// ---------------- init ----------------
__global__ void k_init(int* bucket_cnt, int* bucket_fill, float* gsum) {
    int i = blockIdx.x * blockDim.x + threadIdx.x;
    if (i < 513) { bucket_cnt[i] = 0; bucket_fill[i] = 0; }
    if (i < NG * HID) gsum[i] = 0.0f;
}

// ---------------- binned CSR build ----------------
// bucket = col >> 8 (256 nodes per bucket, nbk = ceil(N/256) = 391)

// Pass A: bucket histogram, LDS-aggregated
__global__ __launch_bounds__(256) void k_bhist(const int* __restrict__ col,
                                               int* __restrict__ bucket_cnt, int e, int nbk) {
    __shared__ int hist[512];
    int tid = threadIdx.x;
    for (int i = tid; i < nbk; i += 256) hist[i] = 0;
    __syncthreads();
    for (int i = blockIdx.x * 256 + tid; i < e; i += 256 * 256)
        atomicAdd(&hist[col[i] >> 8], 1);
    __syncthreads();
    for (int i = tid; i < nbk; i += 256)
        if (hist[i]) atomicAdd(&bucket_cnt[i], hist[i]);
}

// parallel exclusive scan over nb <= 512 elements, in place; data[nb] = total
__global__ void k_scan_small(int* data, int nb) {
    __shared__ int s[512];
    int t = threadIdx.x;
    int v = (t < nb) ? data[t] : 0;
    s[t] = v;
    __syncthreads();
    for (int o = 1; o < 512; o <<= 1) {
        int a = (t >= o) ? s[t - o] : 0;
        __syncthreads();
        s[t] += a;
        __syncthreads();
    }
    if (t < nb) data[t] = s[t] - v;
    if (t == nb - 1) data[nb] = s[t];
}

// Pass C: binned scatter. Each block multisplits 2048 edges by bucket in LDS,
// reserves global space per touched bucket, writes records grouped by bucket.
// Record: x = (col&255)<<17 | src (src < 2^17), y = raw w bits.
__global__ __launch_bounds__(256) void k_bin_scatter(const int* __restrict__ row,
                                                     const int* __restrict__ col,
                                                     const float* __restrict__ w,
                                                     const int* __restrict__ bucket_base,
                                                     int* __restrict__ bucket_fill,
                                                     uint2* __restrict__ binned, int e, int nbk) {
    __shared__ int hist[512], rnk[512], basub[512];
    int tid = threadIdx.x;
    int c0 = blockIdx.x * 2048;
    for (int i = tid; i < nbk; i += 256) { hist[i] = 0; rnk[i] = 0; }
    __syncthreads();
    int myb[8]; unsigned myp[8]; unsigned myw[8];
#pragma unroll
    for (int u = 0; u < 8; ++u) {
        int idx = c0 + u * 256 + tid;
        int b = -1;
        if (idx < e) {
            int c = col[idx];
            int r = row[idx];
            myw[u] = __float_as_uint(w[idx]);
            b = c >> 8;
            myp[u] = ((unsigned)(c & 255) << 17) | (unsigned)r;
            atomicAdd(&hist[b], 1);
        }
        myb[u] = b;
    }
    __syncthreads();
    for (int i = tid; i < nbk; i += 256) {
        int c = hist[i];
        basub[i] = (c > 0) ? (bucket_base[i] + atomicAdd(&bucket_fill[i], c)) : 0;
    }
    __syncthreads();
#pragma unroll
    for (int u = 0; u < 8; ++u) {
        int b = myb[u];
        if (b >= 0) {
            int rk = atomicAdd(&rnk[b], 1);
            binned[basub[b] + rk] = make_uint2(myp[u], myw[u]);
        }
    }
}

// Pass D1: per-bucket node histogram -> cnt (no global atomics)
__global__ __launch_bounds__(256) void k_bucket_cnt(const uint2* __restrict__ binned,
                                                    const int* __restrict__ bucket_base,
                                                    int* __restrict__ cnt, int n) {
    __shared__ int c256[256];
    int b = blockIdx.x, tid = threadIdx.x;
    c256[tid] = 0;
    __syncthreads();
    int beg = bucket_base[b], end = bucket_base[b + 1];
    for (int e2 = beg + tid; e2 < end; e2 += 256)
        atomicAdd(&c256[(binned[e2].x >> 17) & 255], 1);
    __syncthreads();
    int node = b * 256 + tid;
    if (node < n) cnt[node] = c256[tid];
}

#define SCAN_B 1024
__global__ void k_scan1(const int* __restrict__ cnt, int* __restrict__ rowptr,
                        int* __restrict__ bsums, int n) {
    __shared__ int s[SCAN_B];
    int t = threadIdx.x;
    int i = blockIdx.x * SCAN_B + t;
    int v = (i < n) ? cnt[i] : 0;
    s[t] = v;
    __syncthreads();
    for (int o = 1; o < SCAN_B; o <<= 1) {
        int a = (t >= o) ? s[t - o] : 0;
        __syncthreads();
        s[t] += a;
        __syncthreads();
    }
    if (i < n) rowptr[i] = s[t] - v;          // exclusive within block
    if (t == SCAN_B - 1) bsums[blockIdx.x] = s[t];
}

__global__ void k_scan3(int* rowptr, const int* __restrict__ bsums, int n, int etot) {
    int i = blockIdx.x * blockDim.x + threadIdx.x;
    if (i < n) rowptr[i] += bsums[i >> 10];
    else if (i == n) rowptr[n] = etot;
}

// Pass D2: per-bucket final scatter; writes land within the bucket's ~32KB
// CSR extent -> L2-absorbed, full lines to HBM.
__global__ __launch_bounds__(256) void k_bucket_scatter(const uint2* __restrict__ binned,
                                                        const int* __restrict__ bucket_base,
                                                        const int* __restrict__ rowptr,
                                                        int2* __restrict__ csr, int n) {
    __shared__ int f256[256];
    int b = blockIdx.x, tid = threadIdx.x;
    f256[tid] = 0;
    __syncthreads();
    int beg = bucket_base[b], end = bucket_base[b + 1];
    for (int e2 = beg + tid; e2 < end; e2 += 256) {
        uint2 rec = binned[e2];
        int lo = (rec.x >> 17) & 255;
        int node = (b << 8) | lo;
        int src = rec.x & 0x1FFFF;
        int pos = rowptr[node] + atomicAdd(&f256[lo], 1);
        csr[pos] = make_int2(src, (int)rec.y);
    }
    (void)n;
}

// deg[i] = 1 (self loop) + sum of raw weights into i; dinv = deg^-1/2
__global__ void k_deg(const int* __restrict__ rowptr, const int2* __restrict__ csr,
                      float* __restrict__ dinv, float* __restrict__ selfn, int n) {
    int i = blockIdx.x * blockDim.x + threadIdx.x;
    if (i >= n) return;
    int beg = rowptr[i], end = rowptr[i + 1];
    float d = 1.0f;
    for (int e = beg; e < end; ++e) d += __int_as_float(csr[e].y);
    float di = (d > 0.0f) ? (1.0f / sqrtf(d)) : 0.0f;
    dinv[i] = di;
    selfn[i] = di * di;
}

// csr_w[e] = dinv[src]*w*dinv[dst]
__global__ void k_norm(const int* __restrict__ rowptr, int2* __restrict__ csr,
                       const float* __restrict__ dinv, int n) {
    int i = blockIdx.x * blockDim.x + threadIdx.x;
    if (i >= n) return;
    float dc = dinv[i];
    int beg = rowptr[i], end = rowptr[i + 1];
    for (int e = beg; e < end; ++e) {
        int2 v = csr[e];
        float nw = dinv[v.x] * __int_as_float(v.y) * dc;
        csr[e] = make_int2(v.x, __float_as_int(nw));
    }
}

// ---------------- fused weights: M = We@W1 [33x128], v = be@W1 [128] ----------------
__global__ void k_combine(const float* __restrict__ We, const float* __restrict__ W1,
                          const float* __restrict__ be,
                          float* __restrict__ M, float* __restrict__ v) {
    int f = threadIdx.x;            // 128
    int k = blockIdx.x;             // 0..33; 33 => bias row
    if (k < IN_DIM) {
        float a = 0.0f;
#pragma unroll 8
        for (int j = 0; j < HID; ++j) a += We[k * HID + j] * W1[j * HID + f];
        M[k * HID + f] = a;
    } else {
        float a = 0.0f;
#pragma unroll 8
        for (int j = 0; j < HID; ++j) a += be[j] * W1[j * HID + f];
        v[f] = a;
    }
}

// ---------------- t = bf16(x@M + v)  (N x 33 @ 33 x 128) ----------------
__global__ __launch_bounds__(256) void k_gemm_x(const float* __restrict__ x,
                                                const float* __restrict__ M,
                                                const float* __restrict__ v,
                                                unsigned short* __restrict__ tb, int n) {
    __shared__ float sX[32 * IN_DIM];
    int n0 = blockIdx.x * 32;
    int tid = threadIdx.x;
    int cnt = n - n0; if (cnt > 32) cnt = 32;
    for (int idx = tid; idx < cnt * IN_DIM; idx += 256)
        sX[idx] = x[szmul(n0, IN_DIM) + idx];
    __syncthreads();
    int f = tid & 127, g = tid >> 7;
    float Mc[IN_DIM];
#pragma unroll
    for (int k = 0; k < IN_DIM; ++k) Mc[k] = M[k * HID + f];
    float vf = v[f];
    int ndEnd = g * 16 + 16; if (ndEnd > cnt) ndEnd = cnt;
    for (int nd = g * 16; nd < ndEnd; ++nd) {
        float a = vf;
#pragma unroll
        for (int k = 0; k < IN_DIM; ++k) a += sX[nd * IN_DIM + k] * Mc[k];
        tb[szmul(n0 + nd, HID) + f] = f2bf(a);
    }
}

// ---------------- GEMM: T = A @ W  (A: n x 128 bf16-packed, W fp32, T bf16) -------
__global__ __launch_bounds__(256) void k_gemm(const unsigned* __restrict__ A,
                                              const float* __restrict__ W,
                                              unsigned short* __restrict__ Tb, int n) {
    __shared__ unsigned sA[64][64];
    int b0 = blockIdx.x * 64;
    int tid = threadIdx.x;
#pragma unroll
    for (int u = 0; u < 4; ++u) {
        int idx = u * 256 + tid;
        int r = idx >> 4, c4 = idx & 15;      // 16 uint4 per row
        uint4 val = make_uint4(0, 0, 0, 0);
        if (b0 + r < n)
            val = *reinterpret_cast<const uint4*>(A + szmul(b0 + r, 64) + c4 * 4);
        *reinterpret_cast<uint4*>(&sA[r][c4 * 4]) = val;
    }
    __syncthreads();
    int ty = tid >> 5, tx = tid & 31;
    float acc0[8], acc1[8], acc2[8], acc3[8];
#pragma unroll
    for (int j = 0; j < 8; ++j) { acc0[j] = 0.f; acc1[j] = 0.f; acc2[j] = 0.f; acc3[j] = 0.f; }
    const float* Wp = W + tx * 4;
    for (int k2 = 0; k2 < 64; ++k2) {
        float4 we = *reinterpret_cast<const float4*>(Wp + (size_t)(2 * k2) * HID);
        float4 wo = *reinterpret_cast<const float4*>(Wp + (size_t)(2 * k2 + 1) * HID);
#pragma unroll
        for (int j = 0; j < 8; ++j) {
            unsigned p = sA[ty * 8 + j][k2];
            float ae = bf_lo(p), ao = bf_hi(p);
            acc0[j] += ae * we.x + ao * wo.x;
            acc1[j] += ae * we.y + ao * wo.y;
            acc2[j] += ae * we.z + ao * wo.z;
            acc3[j] += ae * we.w + ao * wo.w;
        }
    }
#pragma unroll
    for (int j = 0; j < 8; ++j) {
        int r = b0 + ty * 8 + j;
        if (r < n) {
            ushort4 o = make_ushort4(f2bf(acc0[j]), f2bf(acc1[j]),
                                     f2bf(acc2[j]), f2bf(acc3[j]));
            *reinterpret_cast<ushort4*>(&Tb[szmul(r, HID) + tx * 4]) = o;
        }
    }
}

// ---------------- aggregate: h[i] = relu(b + selfn[i]*t[i] + sum_e w_e * t[src_e]) ----
// Quarter-wave gather: 4 edges/iteration. Lane = (quarter, p); quarter q processes
// edge j+q; its 16 lanes load uint4 (16B x 16 = 256B row). 4 VALU/edge.
// Cross-quarter reduce via shfl_xor(16|32) once at the end.
__global__ __launch_bounds__(256) void k_aggregate(const uint4* __restrict__ tb,
                                                   const int* __restrict__ rowptr,
                                                   const int2* __restrict__ csr,
                                                   const float* __restrict__ selfn,
                                                   const float* __restrict__ bias,
                                                   uint4* __restrict__ hout, int n) {
    int i = (blockIdx.x * 256 + threadIdx.x) >> 6;
    if (i >= n) return;
    int lane = threadIdx.x & 63;
    int quarter = lane >> 4;
    int p = lane & 15;                        // uint4 index in row; features 8p..8p+7
    float a0 = 0.f, a1 = 0.f, a2 = 0.f, a3 = 0.f;
    float a4 = 0.f, a5 = 0.f, a6 = 0.f, a7 = 0.f;
    if (quarter == 0) {
        uint4 sv = tb[szmul(i, 16) + p];
        float sn = selfn[i];
        const float4* bp = reinterpret_cast<const float4*>(bias + p * 8);
        float4 b0 = bp[0], b1 = bp[1];
        a0 = b0.x + sn * bf_lo(sv.x); a1 = b0.y + sn * bf_hi(sv.x);
        a2 = b0.z + sn * bf_lo(sv.y); a3 = b0.w + sn * bf_hi(sv.y);
        a4 = b1.x + sn * bf_lo(sv.z); a5 = b1.y + sn * bf_hi(sv.z);
        a6 = b1.z + sn * bf_lo(sv.w); a7 = b1.w + sn * bf_hi(sv.w);
    }
    int beg = rowptr[i], end = rowptr[i + 1];
    for (int base = beg; base < end; base += 64) {
        int m = end - base; if (m > 64) m = 64;
        int2 e = make_int2(0, 0);
        if (lane < m) e = csr[base + lane];
#pragma unroll 2
        for (int j = 0; j < m; j += 4) {
            int jj = j + quarter;             // quarter q handles edge j+q
            int src = __shfl(e.x, jj);        // (0,0) beyond m -> w=0, contributes 0
            float wj = __int_as_float(__shfl(e.y, jj));
            uint4 r = tb[szmul(src, 16) + p];
            a0 += wj * bf_lo(r.x); a1 += wj * bf_hi(r.x);
            a2 += wj * bf_lo(r.y); a3 += wj * bf_hi(r.y);
            a4 += wj * bf_lo(r.z); a5 += wj * bf_hi(r.z);
            a6 += wj * bf_lo(r.w); a7 += wj * bf_hi(r.w);
        }
    }
    a0 += __shfl_xor(a0, 16); a1 += __shfl_xor(a1, 16);
    a2 += __shfl_xor(a2, 16); a3 += __shfl_xor(a3, 16);
    a4 += __shfl_xor(a4, 16); a5 += __shfl_xor(a5, 16);
    a6 += __shfl_xor(a6, 16); a7 += __shfl_xor(a7, 16);
    a0 += __shfl_xor(a0, 32); a1 += __shfl_xor(a1, 32);
    a2 += __shfl_xor(a2, 32); a3 += __shfl_xor(a3, 32);
    a4 += __shfl_xor(a4, 32); a5 += __shfl_xor(a5, 32);
    a6 += __shfl_xor(a6, 32); a7 += __shfl_xor(a7, 32);
    if (quarter == 0) {
        unsigned u0 = (unsigned)f2bf(fmaxf(a0, 0.f)) | ((unsigned)f2bf(fmaxf(a1, 0.f)) << 16);
        unsigned u1 = (unsigned)f2bf(fmaxf(a2, 0.f)) | ((unsigned)f2bf(fmaxf(a3, 0.f)) << 16);
        unsigned u2 = (unsigned)f2bf(fmaxf(a4, 0.f)) | ((unsigned)f2bf(fmaxf(a5, 0.f)) << 16);
        unsigned u3 = (unsigned)f2bf(fmaxf(a6, 0.f)) | ((unsigned)f2bf(fmaxf(a7, 0.f)) << 16);
        hout[szmul(i, 16) + p] = make_uint4(u0, u1, u2, u3);
    }
}

// ---------------- pooling ----------------
__global__ void k_gcount_bs(const int* __restrict__ batch, int* gcnt, int n) {
    int g = threadIdx.x;
    if (g >= NG) return;
    int lo = 0, hi = n;
    while (lo < hi) { int mid = (lo + hi) >> 1; if (batch[mid] < g) lo = mid + 1; else hi = mid; }
    int start = lo;
    lo = 0; hi = n;
    while (lo < hi) { int mid = (lo + hi) >> 1; if (batch[mid] < g + 1) lo = mid + 1; else hi = mid; }
    gcnt[g] = lo - start;
}

__global__ __launch_bounds__(128) void k_pool(const unsigned short* __restrict__ h,
                                              const int* __restrict__ batch,
                                              float* gsum, int n) {
    int f = threadIdx.x;
    int i0 = blockIdx.x * 32;
    int i1 = min(i0 + 32, n);
    if (i0 >= n) return;
    float acc = 0.0f;
    int cur = batch[i0];
    for (int i = i0; i < i1; ++i) {
        int g = batch[i];
        if (g != cur) { atomicAdd(&gsum[cur * HID + f], acc); acc = 0.0f; cur = g; }
        acc += __uint_as_float((unsigned)h[szmul(i, HID) + f] << 16);
    }
    atomicAdd(&gsum[cur * HID + f], acc);
}

// ---------------- readout MLP ----------------
__global__ __launch_bounds__(128) void k_mlp(const float* __restrict__ gsum,
                                             const int* __restrict__ gcnt,
                                             const float* __restrict__ Wr1, const float* __restrict__ br1,
                                             const float* __restrict__ Wr2, const float* __restrict__ br2,
                                             const float* __restrict__ Wr3,
                                             float* __restrict__ out) {
    int g = blockIdx.x;
    int t = threadIdx.x;
    __shared__ float p[HID];
    __shared__ float r1[64];
    __shared__ float r2[32];
    float c = fmaxf((float)gcnt[g], 1.0f);
    p[t] = gsum[g * HID + t] / c;
    __syncthreads();
    if (t < 64) {
        float a = br1[t];
#pragma unroll 8
        for (int k = 0; k < HID; ++k) a += p[k] * Wr1[k * 64 + t];
        r1[t] = fmaxf(a, 0.0f);
    }
    __syncthreads();
    if (t < 32) {
        float a = br2[t];
#pragma unroll 8
        for (int k = 0; k < 64; ++k) a += r1[k] * Wr2[k * 32 + t];
        r2[t] = fmaxf(a, 0.0f);
    }
    __syncthreads();
    if (t < NCLS) {
        float a = 0.0f;
#pragma unroll
        for (int k = 0; k < 32; ++k) a += r2[k] * Wr3[k * NCLS + t];
        out[g * NCLS + t] = a;
    }
}

extern "C" void kernel_launch(void* const* d_in, const int* in_sizes, int n_in,
                              void* d_out, int out_size, void* d_ws, size_t ws_size,
                              hipStream_t stream) {
    const float* x     = (const float*)d_in[0];
    const int*   ei    = (const int*)d_in[1];
    const float* ew    = (const float*)d_in[2];
    const int*   batch = (const int*)d_in[3];
    const float* We  = (const float*)d_in[4];
    const float* be  = (const float*)d_in[5];
    const float* Wl[4] = { (const float*)d_in[6], (const float*)d_in[8],
                           (const float*)d_in[10], (const float*)d_in[12] };
    const float* bl[4] = { (const float*)d_in[7], (const float*)d_in[9],
                           (const float*)d_in[11], (const float*)d_in[13] };
    const float* Wr1 = (const float*)d_in[14];
    const float* br1 = (const float*)d_in[15];
    const float* Wr2 = (const float*)d_in[16];
    const float* br2 = (const float*)d_in[17];
    const float* Wr3 = (const float*)d_in[18];
    float* out = (float*)d_out;

    const int N = in_sizes[3];      // 100000
    const int E = in_sizes[2];      // 1600000
    const int* row = ei;
    const int* col = ei + E;
    const int nbk = (N + 255) >> 8; // 391 buckets

    // workspace layout
    char* w = (char*)d_ws;
    size_t off = 0;
    auto alloc = [&](size_t bytes) -> void* {
        void* p = w + off;
        off = (off + bytes + 255) & ~(size_t)255;
        return p;
    };
    float* dinv       = (float*)alloc((size_t)N * 4);
    float* selfn      = (float*)alloc((size_t)N * 4);
    int*   cnt        = (int*)  alloc((size_t)N * 4);
    int*   rowptr     = (int*)  alloc((size_t)(N + 1) * 4);
    int*   bsums      = (int*)  alloc(4096);
    int*   bucket_cnt = (int*)  alloc(513 * 4);   // becomes bucket_base after scan
    int*   bucket_fill= (int*)  alloc(513 * 4);
    int2*  csr        = (int2*) alloc((size_t)E * 8);
    unsigned short* h  = (unsigned short*)alloc((size_t)N * HID * 2);  // bf16 activations
    unsigned short* tb = (unsigned short*)alloc((size_t)N * HID * 2);  // bf16 messages
    float* M          = (float*)alloc((size_t)IN_DIM * HID * 4);
    float* vbe        = (float*)alloc((size_t)HID * 4);
    float* gsum       = (float*)alloc((size_t)NG * HID * 4);
    int*   gcnt       = (int*)  alloc((size_t)NG * 4);
    uint2* binned     = (uint2*)tb;  // alias: consumed by D1/D2 before tb first written
    (void)ws_size;

    auto cdiv = [](int a, int b) { return (a + b - 1) / b; };

    // ---- binned CSR build ----
    k_init<<<64, 256, 0, stream>>>(bucket_cnt, bucket_fill, gsum);
    k_bhist<<<256, 256, 0, stream>>>(col, bucket_cnt, E, nbk);
    k_scan_small<<<1, 512, 0, stream>>>(bucket_cnt, nbk);        // -> bucket_base
    k_bin_scatter<<<cdiv(E, 2048), 256, 0, stream>>>(row, col, ew, bucket_cnt,
                                                     bucket_fill, binned, E, nbk);
    k_bucket_cnt<<<nbk, 256, 0, stream>>>(binned, bucket_cnt, cnt, N);

    int nb = cdiv(N, SCAN_B);
    k_scan1<<<nb, SCAN_B, 0, stream>>>(cnt, rowptr, bsums, N);
    k_scan_small<<<1, 512, 0, stream>>>(bsums, nb);
    k_scan3<<<cdiv(N + 1, 256), 256, 0, stream>>>(rowptr, bsums, N, E);
    k_bucket_scatter<<<nbk, 256, 0, stream>>>(binned, bucket_cnt, rowptr, csr, N);

    k_deg<<<cdiv(N, 256), 256, 0, stream>>>(rowptr, csr, dinv, selfn, N);
    k_norm<<<cdiv(N, 256), 256, 0, stream>>>(rowptr, csr, dinv, N);

    // layer 1: t = bf16(x@(We@W1) + be@W1); h = relu(agg(t) + b1)
    k_combine<<<IN_DIM + 1, HID, 0, stream>>>(We, Wl[0], be, M, vbe);
    k_gemm_x<<<cdiv(N, 32), 256, 0, stream>>>(x, M, vbe, tb, N);
    k_aggregate<<<cdiv(N, 4), 256, 0, stream>>>((const uint4*)tb, rowptr, csr,
                                                selfn, bl[0], (uint4*)h, N);

    // layers 2-4: bf16 GEMM + bf16 aggregate
    for (int l = 1; l < 4; ++l) {
        k_gemm<<<cdiv(N, 64), 256, 0, stream>>>((const unsigned*)h, Wl[l], tb, N);
        k_aggregate<<<cdiv(N, 4), 256, 0, stream>>>((const uint4*)tb, rowptr, csr,
                                                    selfn, bl[l], (uint4*)h, N);
    }

    k_gcount_bs<<<1, 128, 0, stream>>>(batch, gcnt, N);
    k_pool<<<cdiv(N, 32), 128, 0, stream>>>(h, batch, gsum, N);
    k_mlp<<<NG, HID, 0, stream>>>(gsum, gcnt, Wr1, br1, Wr2, br2, Wr3, out);

    (void)out_size; (void)n_in;
}

// Round 11
// 538.672 us; speedup vs baseline: 1.7774x; 1.1689x over previous
//
#include <hip/hip_runtime.h>
#include <hip/hip_bf16.h>

#define NN 100000
#define NE 1600000
#define IN_DIM 33
#define HID 128
#define NG 128
#define NCLS 10

using short8 = __attribute__((ext_vector_type(8))) short;
using floatx4 = __attribute__((ext_vector_type(4))) float;

static __device__ __forceinline__ size_t szmul(int a, int b) {
    return (size_t)a * (size_t)b;
}

// bf16 helpers: pack with RNE, unpack via bit ops (cheap: 1 VALU each)
static __device__ __forceinline__ unsigned short f2bf(float f) {
    unsigned u = __float_as_uint(f);
    u += 0x7fffu + ((u >> 16) & 1u);
    return (unsigned short)(u >> 16);
}
static __device__ __forceinline__ float bf_lo(unsigned u) { return __uint_as_float(u << 16); }
static __device__ __forceinline__ float bf_hi(unsigned u) { return __uint_as_float(u & 0xffff0000u); }

// ---------------- init ----------------
__global__ void k_init(int* bucket_cnt, int* bucket_fill, float* gsum) {
    int i = blockIdx.x * blockDim.x + threadIdx.x;
    if (i < 513) { bucket_cnt[i] = 0; bucket_fill[i] = 0; }
    if (i < NG * HID) gsum[i] = 0.0f;
}

// ---------------- binned CSR build ----------------
// bucket = col >> 8 (256 nodes per bucket, nbk = ceil(N/256) = 391)

// Pass A: bucket histogram, LDS-aggregated
__global__ __launch_bounds__(256) void k_bhist(const int* __restrict__ col,
                                               int* __restrict__ bucket_cnt, int e, int nbk) {
    __shared__ int hist[512];
    int tid = threadIdx.x;
    for (int i = tid; i < nbk; i += 256) hist[i] = 0;
    __syncthreads();
    for (int i = blockIdx.x * 256 + tid; i < e; i += 256 * 256)
        atomicAdd(&hist[col[i] >> 8], 1);
    __syncthreads();
    for (int i = tid; i < nbk; i += 256)
        if (hist[i]) atomicAdd(&bucket_cnt[i], hist[i]);
}

// parallel exclusive scan over nb <= 512 elements, in place; data[nb] = total
__global__ void k_scan_small(int* data, int nb) {
    __shared__ int s[512];
    int t = threadIdx.x;
    int v = (t < nb) ? data[t] : 0;
    s[t] = v;
    __syncthreads();
    for (int o = 1; o < 512; o <<= 1) {
        int a = (t >= o) ? s[t - o] : 0;
        __syncthreads();
        s[t] += a;
        __syncthreads();
    }
    if (t < nb) data[t] = s[t] - v;
    if (t == nb - 1) data[nb] = s[t];
}

// Pass C: binned scatter. Each block multisplits 2048 edges by bucket in LDS,
// reserves global space per touched bucket, writes records grouped by bucket.
// Record: x = (col&255)<<17 | src (src < 2^17), y = raw w bits.
__global__ __launch_bounds__(256) void k_bin_scatter(const int* __restrict__ row,
                                                     const int* __restrict__ col,
                                                     const float* __restrict__ w,
                                                     const int* __restrict__ bucket_base,
                                                     int* __restrict__ bucket_fill,
                                                     uint2* __restrict__ binned, int e, int nbk) {
    __shared__ int hist[512], rnk[512], basub[512];
    int tid = threadIdx.x;
    int c0 = blockIdx.x * 2048;
    for (int i = tid; i < nbk; i += 256) { hist[i] = 0; rnk[i] = 0; }
    __syncthreads();
    int myb[8]; unsigned myp[8]; unsigned myw[8];
#pragma unroll
    for (int u = 0; u < 8; ++u) {
        int idx = c0 + u * 256 + tid;
        int b = -1;
        if (idx < e) {
            int c = col[idx];
            int r = row[idx];
            myw[u] = __float_as_uint(w[idx]);
            b = c >> 8;
            myp[u] = ((unsigned)(c & 255) << 17) | (unsigned)r;
            atomicAdd(&hist[b], 1);
        }
        myb[u] = b;
    }
    __syncthreads();
    for (int i = tid; i < nbk; i += 256) {
        int c = hist[i];
        basub[i] = (c > 0) ? (bucket_base[i] + atomicAdd(&bucket_fill[i], c)) : 0;
    }
    __syncthreads();
#pragma unroll
    for (int u = 0; u < 8; ++u) {
        int b = myb[u];
        if (b >= 0) {
            int rk = atomicAdd(&rnk[b], 1);
            binned[basub[b] + rk] = make_uint2(myp[u], myw[u]);
        }
    }
}

// Pass D1: per-bucket node histogram -> cnt (no global atomics)
__global__ __launch_bounds__(256) void k_bucket_cnt(const uint2* __restrict__ binned,
                                                    const int* __restrict__ bucket_base,
                                                    int* __restrict__ cnt, int n) {
    __shared__ int c256[256];
    int b = blockIdx.x, tid = threadIdx.x;
    c256[tid] = 0;
    __syncthreads();
    int beg = bucket_base[b], end = bucket_base[b + 1];
    for (int e2 = beg + tid; e2 < end; e2 += 256)
        atomicAdd(&c256[(binned[e2].x >> 17) & 255], 1);
    __syncthreads();
    int node = b * 256 + tid;
    if (node < n) cnt[node] = c256[tid];
}

#define SCAN_B 1024
__global__ void k_scan1(const int* __restrict__ cnt, int* __restrict__ rowptr,
                        int* __restrict__ bsums, int n) {
    __shared__ int s[SCAN_B];
    int t = threadIdx.x;
    int i = blockIdx.x * SCAN_B + t;
    int v = (i < n) ? cnt[i] : 0;
    s[t] = v;
    __syncthreads();
    for (int o = 1; o < SCAN_B; o <<= 1) {
        int a = (t >= o) ? s[t - o] : 0;
        __syncthreads();
        s[t] += a;
        __syncthreads();
    }
    if (i < n) rowptr[i] = s[t] - v;          // exclusive within block
    if (t == SCAN_B - 1) bsums[blockIdx.x] = s[t];
}

__global__ void k_scan3(int* rowptr, const int* __restrict__ bsums, int n, int etot) {
    int i = blockIdx.x * blockDim.x + threadIdx.x;
    if (i < n) rowptr[i] += bsums[i >> 10];
    else if (i == n) rowptr[n] = etot;
}

// Pass D2: per-bucket final scatter; writes land within the bucket's ~32KB
// CSR extent -> L2-absorbed, full lines to HBM.
__global__ __launch_bounds__(256) void k_bucket_scatter(const uint2* __restrict__ binned,
                                                        const int* __restrict__ bucket_base,
                                                        const int* __restrict__ rowptr,
                                                        int2* __restrict__ csr, int n) {
    __shared__ int f256[256];
    int b = blockIdx.x, tid = threadIdx.x;
    f256[tid] = 0;
    __syncthreads();
    int beg = bucket_base[b], end = bucket_base[b + 1];
    for (int e2 = beg + tid; e2 < end; e2 += 256) {
        uint2 rec = binned[e2];
        int lo = (rec.x >> 17) & 255;
        int node = (b << 8) | lo;
        int src = rec.x & 0x1FFFF;
        int pos = rowptr[node] + atomicAdd(&f256[lo], 1);
        csr[pos] = make_int2(src, (int)rec.y);
    }
    (void)n;
}

// deg[i] = 1 (self loop) + sum of raw weights into i; dinv = deg^-1/2
__global__ void k_deg(const int* __restrict__ rowptr, const int2* __restrict__ csr,
                      float* __restrict__ dinv, float* __restrict__ selfn, int n) {
    int i = blockIdx.x * blockDim.x + threadIdx.x;
    if (i >= n) return;
    int beg = rowptr[i], end = rowptr[i + 1];
    float d = 1.0f;
    for (int e = beg; e < end; ++e) d += __int_as_float(csr[e].y);
    float di = (d > 0.0f) ? (1.0f / sqrtf(d)) : 0.0f;
    dinv[i] = di;
    selfn[i] = di * di;
}

// csr_w[e] = dinv[src]*w*dinv[dst]
__global__ void k_norm(const int* __restrict__ rowptr, int2* __restrict__ csr,
                       const float* __restrict__ dinv, int n) {
    int i = blockIdx.x * blockDim.x + threadIdx.x;
    if (i >= n) return;
    float dc = dinv[i];
    int beg = rowptr[i], end = rowptr[i + 1];
    for (int e = beg; e < end; ++e) {
        int2 v = csr[e];
        float nw = dinv[v.x] * __int_as_float(v.y) * dc;
        csr[e] = make_int2(v.x, __float_as_int(nw));
    }
}

// ---------------- fused weights: M = We@W1 [33x128], v = be@W1 [128] ----------------
__global__ void k_combine(const float* __restrict__ We, const float* __restrict__ W1,
                          const float* __restrict__ be,
                          float* __restrict__ M, float* __restrict__ v) {
    int f = threadIdx.x;            // 128
    int k = blockIdx.x;             // 0..33; 33 => bias row
    if (k < IN_DIM) {
        float a = 0.0f;
#pragma unroll 8
        for (int j = 0; j < HID; ++j) a += We[k * HID + j] * W1[j * HID + f];
        M[k * HID + f] = a;
    } else {
        float a = 0.0f;
#pragma unroll 8
        for (int j = 0; j < HID; ++j) a += be[j] * W1[j * HID + f];
        v[f] = a;
    }
}

// ---------------- W transpose+cast: Wt[l][c][k] = bf16(W_l[k][c]) ----------------
__global__ void k_wcast3(const float* __restrict__ W1, const float* __restrict__ W2,
                         const float* __restrict__ W3, unsigned short* __restrict__ Wt) {
    int k = blockIdx.x, c = threadIdx.x, l = blockIdx.y;
    const float* W = (l == 0) ? W1 : (l == 1) ? W2 : W3;
    Wt[((size_t)l * HID + c) * HID + k] = f2bf(W[k * HID + c]);
}

// ---------------- t = bf16(x@M + v)  (N x 33 @ 33 x 128) ----------------
__global__ __launch_bounds__(256) void k_gemm_x(const float* __restrict__ x,
                                                const float* __restrict__ M,
                                                const float* __restrict__ v,
                                                unsigned short* __restrict__ tb, int n) {
    __shared__ float sX[32 * IN_DIM];
    int n0 = blockIdx.x * 32;
    int tid = threadIdx.x;
    int cnt = n - n0; if (cnt > 32) cnt = 32;
    for (int idx = tid; idx < cnt * IN_DIM; idx += 256)
        sX[idx] = x[szmul(n0, IN_DIM) + idx];
    __syncthreads();
    int f = tid & 127, g = tid >> 7;
    float Mc[IN_DIM];
#pragma unroll
    for (int k = 0; k < IN_DIM; ++k) Mc[k] = M[k * HID + f];
    float vf = v[f];
    int ndEnd = g * 16 + 16; if (ndEnd > cnt) ndEnd = cnt;
    for (int nd = g * 16; nd < ndEnd; ++nd) {
        float a = vf;
#pragma unroll
        for (int k = 0; k < IN_DIM; ++k) a += sX[nd * IN_DIM + k] * Mc[k];
        tb[szmul(n0 + nd, HID) + f] = f2bf(a);
    }
}

// ---------------- MFMA GEMM: T = A @ W  (A: n x 128 bf16, Wt: 128x128 bf16 col-major) ----
// 4 waves/block, wave = 16 rows x 128 cols; no LDS. A frag: lane holds
// A[row0 + (l&15)][kk*32 + (l>>4)*8 + 0..7] (one 16B load). B frag from transposed
// Wt: Wt[ct*16 + (l&15)][kk*32 + (l>>4)*8 + 0..7]. D: col = l&15, row = (l>>4)*4 + reg.
__global__ __launch_bounds__(256) void k_gemm_mfma(const unsigned short* __restrict__ A,
                                                   const unsigned short* __restrict__ Wt,
                                                   unsigned short* __restrict__ T, int n) {
    int wave = threadIdx.x >> 6;
    int lane = threadIdx.x & 63;
    int r = lane & 15, kg = lane >> 4;
    int row0 = blockIdx.x * 64 + wave * 16;
    int arow = row0 + r;
    short8 af[4];
#pragma unroll
    for (int kk = 0; kk < 4; ++kk) {
        if (arow < n)
            af[kk] = *reinterpret_cast<const short8*>(A + szmul(arow, HID) + kk * 32 + kg * 8);
        else
            af[kk] = short8{0, 0, 0, 0, 0, 0, 0, 0};
    }
#pragma unroll
    for (int ct = 0; ct < 8; ++ct) {
        floatx4 acc = {0.f, 0.f, 0.f, 0.f};
#pragma unroll
        for (int kk = 0; kk < 4; ++kk) {
            short8 bf = *reinterpret_cast<const short8*>(
                Wt + (size_t)(ct * 16 + r) * HID + kk * 32 + kg * 8);
            acc = __builtin_amdgcn_mfma_f32_16x16x32_bf16(af[kk], bf, acc, 0, 0, 0);
        }
#pragma unroll
        for (int reg = 0; reg < 4; ++reg) {
            int orow = row0 + kg * 4 + reg;
            if (orow < n)
                T[szmul(orow, HID) + ct * 16 + r] = f2bf(acc[reg]);
        }
    }
}

// ---------------- aggregate: h[i] = relu(b + selfn[i]*t[i] + sum_e w_e * t[src_e]) ----
// Quarter-wave gather: 4 edges/iteration. Lane = (quarter, p); quarter q processes
// edge j+q; its 16 lanes load uint4 (16B x 16 = 256B row). 4 VALU/edge.
__global__ __launch_bounds__(256) void k_aggregate(const uint4* __restrict__ tb,
                                                   const int* __restrict__ rowptr,
                                                   const int2* __restrict__ csr,
                                                   const float* __restrict__ selfn,
                                                   const float* __restrict__ bias,
                                                   uint4* __restrict__ hout, int n) {
    int i = (blockIdx.x * 256 + threadIdx.x) >> 6;
    if (i >= n) return;
    int lane = threadIdx.x & 63;
    int quarter = lane >> 4;
    int p = lane & 15;                        // uint4 index in row; features 8p..8p+7
    float a0 = 0.f, a1 = 0.f, a2 = 0.f, a3 = 0.f;
    float a4 = 0.f, a5 = 0.f, a6 = 0.f, a7 = 0.f;
    if (quarter == 0) {
        uint4 sv = tb[szmul(i, 16) + p];
        float sn = selfn[i];
        const float4* bp = reinterpret_cast<const float4*>(bias + p * 8);
        float4 b0 = bp[0], b1 = bp[1];
        a0 = b0.x + sn * bf_lo(sv.x); a1 = b0.y + sn * bf_hi(sv.x);
        a2 = b0.z + sn * bf_lo(sv.y); a3 = b0.w + sn * bf_hi(sv.y);
        a4 = b1.x + sn * bf_lo(sv.z); a5 = b1.y + sn * bf_hi(sv.z);
        a6 = b1.z + sn * bf_lo(sv.w); a7 = b1.w + sn * bf_hi(sv.w);
    }
    int beg = rowptr[i], end = rowptr[i + 1];
    for (int base = beg; base < end; base += 64) {
        int m = end - base; if (m > 64) m = 64;
        int2 e = make_int2(0, 0);
        if (lane < m) e = csr[base + lane];
#pragma unroll 2
        for (int j = 0; j < m; j += 4) {
            int jj = j + quarter;             // quarter q handles edge j+q
            int src = __shfl(e.x, jj);        // (0,0) beyond m -> w=0, contributes 0
            float wj = __int_as_float(__shfl(e.y, jj));
            uint4 r = tb[szmul(src, 16) + p];
            a0 += wj * bf_lo(r.x); a1 += wj * bf_hi(r.x);
            a2 += wj * bf_lo(r.y); a3 += wj * bf_hi(r.y);
            a4 += wj * bf_lo(r.z); a5 += wj * bf_hi(r.z);
            a6 += wj * bf_lo(r.w); a7 += wj * bf_hi(r.w);
        }
    }
    a0 += __shfl_xor(a0, 16); a1 += __shfl_xor(a1, 16);
    a2 += __shfl_xor(a2, 16); a3 += __shfl_xor(a3, 16);
    a4 += __shfl_xor(a4, 16); a5 += __shfl_xor(a5, 16);
    a6 += __shfl_xor(a6, 16); a7 += __shfl_xor(a7, 16);
    a0 += __shfl_xor(a0, 32); a1 += __shfl_xor(a1, 32);
    a2 += __shfl_xor(a2, 32); a3 += __shfl_xor(a3, 32);
    a4 += __shfl_xor(a4, 32); a5 += __shfl_xor(a5, 32);
    a6 += __shfl_xor(a6, 32); a7 += __shfl_xor(a7, 32);
    if (quarter == 0) {
        unsigned u0 = (unsigned)f2bf(fmaxf(a0, 0.f)) | ((unsigned)f2bf(fmaxf(a1, 0.f)) << 16);
        unsigned u1 = (unsigned)f2bf(fmaxf(a2, 0.f)) | ((unsigned)f2bf(fmaxf(a3, 0.f)) << 16);
        unsigned u2 = (unsigned)f2bf(fmaxf(a4, 0.f)) | ((unsigned)f2bf(fmaxf(a5, 0.f)) << 16);
        unsigned u3 = (unsigned)f2bf(fmaxf(a6, 0.f)) | ((unsigned)f2bf(fmaxf(a7, 0.f)) << 16);
        hout[szmul(i, 16) + p] = make_uint4(u0, u1, u2, u3);
    }
}

// ---------------- pooling ----------------
__global__ void k_gcount_bs(const int* __restrict__ batch, int* gcnt, int n) {
    int g = threadIdx.x;
    if (g >= NG) return;
    int lo = 0, hi = n;
    while (lo < hi) { int mid = (lo + hi) >> 1; if (batch[mid] < g) lo = mid + 1; else hi = mid; }
    int start = lo;
    lo = 0; hi = n;
    while (lo < hi) { int mid = (lo + hi) >> 1; if (batch[mid] < g + 1) lo = mid + 1; else hi = mid; }
    gcnt[g] = lo - start;
}

__global__ __launch_bounds__(128) void k_pool(const unsigned short* __restrict__ h,
                                              const int* __restrict__ batch,
                                              float* gsum, int n) {
    int f = threadIdx.x;
    int i0 = blockIdx.x * 32;
    int i1 = min(i0 + 32, n);
    if (i0 >= n) return;
    float acc = 0.0f;
    int cur = batch[i0];
    for (int i = i0; i < i1; ++i) {
        int g = batch[i];
        if (g != cur) { atomicAdd(&gsum[cur * HID + f], acc); acc = 0.0f; cur = g; }
        acc += __uint_as_float((unsigned)h[szmul(i, HID) + f] << 16);
    }
    atomicAdd(&gsum[cur * HID + f], acc);
}

// ---------------- readout MLP ----------------
__global__ __launch_bounds__(128) void k_mlp(const float* __restrict__ gsum,
                                             const int* __restrict__ gcnt,
                                             const float* __restrict__ Wr1, const float* __restrict__ br1,
                                             const float* __restrict__ Wr2, const float* __restrict__ br2,
                                             const float* __restrict__ Wr3,
                                             float* __restrict__ out) {
    int g = blockIdx.x;
    int t = threadIdx.x;
    __shared__ float p[HID];
    __shared__ float r1[64];
    __shared__ float r2[32];
    float c = fmaxf((float)gcnt[g], 1.0f);
    p[t] = gsum[g * HID + t] / c;
    __syncthreads();
    if (t < 64) {
        float a = br1[t];
#pragma unroll 8
        for (int k = 0; k < HID; ++k) a += p[k] * Wr1[k * 64 + t];
        r1[t] = fmaxf(a, 0.0f);
    }
    __syncthreads();
    if (t < 32) {
        float a = br2[t];
#pragma unroll 8
        for (int k = 0; k < 64; ++k) a += r1[k] * Wr2[k * 32 + t];
        r2[t] = fmaxf(a, 0.0f);
    }
    __syncthreads();
    if (t < NCLS) {
        float a = 0.0f;
#pragma unroll
        for (int k = 0; k < 32; ++k) a += r2[k] * Wr3[k * NCLS + t];
        out[g * NCLS + t] = a;
    }
}

extern "C" void kernel_launch(void* const* d_in, const int* in_sizes, int n_in,
                              void* d_out, int out_size, void* d_ws, size_t ws_size,
                              hipStream_t stream) {
    const float* x     = (const float*)d_in[0];
    const int*   ei    = (const int*)d_in[1];
    const float* ew    = (const float*)d_in[2];
    const int*   batch = (const int*)d_in[3];
    const float* We  = (const float*)d_in[4];
    const float* be  = (const float*)d_in[5];
    const float* Wl[4] = { (const float*)d_in[6], (const float*)d_in[8],
                           (const float*)d_in[10], (const float*)d_in[12] };
    const float* bl[4] = { (const float*)d_in[7], (const float*)d_in[9],
                           (const float*)d_in[11], (const float*)d_in[13] };
    const float* Wr1 = (const float*)d_in[14];
    const float* br1 = (const float*)d_in[15];
    const float* Wr2 = (const float*)d_in[16];
    const float* br2 = (const float*)d_in[17];
    const float* Wr3 = (const float*)d_in[18];
    float* out = (float*)d_out;

    const int N = in_sizes[3];      // 100000
    const int E = in_sizes[2];      // 1600000
    const int* row = ei;
    const int* col = ei + E;
    const int nbk = (N + 255) >> 8; // 391 buckets

    // workspace layout
    char* w = (char*)d_ws;
    size_t off = 0;
    auto alloc = [&](size_t bytes) -> void* {
        void* p = w + off;
        off = (off + bytes + 255) & ~(size_t)255;
        return p;
    };
    float* dinv       = (float*)alloc((size_t)N * 4);
    float* selfn      = (float*)alloc((size_t)N * 4);
    int*   cnt        = (int*)  alloc((size_t)N * 4);
    int*   rowptr     = (int*)  alloc((size_t)(N + 1) * 4);
    int*   bsums      = (int*)  alloc(4096);
    int*   bucket_cnt = (int*)  alloc(513 * 4);   // becomes bucket_base after scan
    int*   bucket_fill= (int*)  alloc(513 * 4);
    int2*  csr        = (int2*) alloc((size_t)E * 8);
    unsigned short* h  = (unsigned short*)alloc((size_t)N * HID * 2);  // bf16 activations
    unsigned short* tb = (unsigned short*)alloc((size_t)N * HID * 2);  // bf16 messages
    unsigned short* Wt = (unsigned short*)alloc((size_t)3 * HID * HID * 2); // bf16 W^T x3
    float* M          = (float*)alloc((size_t)IN_DIM * HID * 4);
    float* vbe        = (float*)alloc((size_t)HID * 4);
    float* gsum       = (float*)alloc((size_t)NG * HID * 4);
    int*   gcnt       = (int*)  alloc((size_t)NG * 4);
    uint2* binned     = (uint2*)tb;  // alias: consumed by D1/D2 before tb first written
    (void)ws_size;

    auto cdiv = [](int a, int b) { return (a + b - 1) / b; };

    // ---- binned CSR build ----
    k_init<<<64, 256, 0, stream>>>(bucket_cnt, bucket_fill, gsum);
    k_bhist<<<256, 256, 0, stream>>>(col, bucket_cnt, E, nbk);
    k_scan_small<<<1, 512, 0, stream>>>(bucket_cnt, nbk);        // -> bucket_base
    k_bin_scatter<<<cdiv(E, 2048), 256, 0, stream>>>(row, col, ew, bucket_cnt,
                                                     bucket_fill, binned, E, nbk);
    k_bucket_cnt<<<nbk, 256, 0, stream>>>(binned, bucket_cnt, cnt, N);

    int nb = cdiv(N, SCAN_B);
    k_scan1<<<nb, SCAN_B, 0, stream>>>(cnt, rowptr, bsums, N);
    k_scan_small<<<1, 512, 0, stream>>>(bsums, nb);
    k_scan3<<<cdiv(N + 1, 256), 256, 0, stream>>>(rowptr, bsums, N, E);
    k_bucket_scatter<<<nbk, 256, 0, stream>>>(binned, bucket_cnt, rowptr, csr, N);

    k_deg<<<cdiv(N, 256), 256, 0, stream>>>(rowptr, csr, dinv, selfn, N);
    k_norm<<<cdiv(N, 256), 256, 0, stream>>>(rowptr, csr, dinv, N);

    // fused layer-1 weights + bf16 transposed W for layers 2-4
    k_combine<<<IN_DIM + 1, HID, 0, stream>>>(We, Wl[0], be, M, vbe);
    k_wcast3<<<dim3(HID, 3), HID, 0, stream>>>(Wl[1], Wl[2], Wl[3], Wt);

    // layer 1: t = bf16(x@(We@W1) + be@W1); h = relu(agg(t) + b1)
    k_gemm_x<<<cdiv(N, 32), 256, 0, stream>>>(x, M, vbe, tb, N);
    k_aggregate<<<cdiv(N, 4), 256, 0, stream>>>((const uint4*)tb, rowptr, csr,
                                                selfn, bl[0], (uint4*)h, N);

    // layers 2-4: MFMA bf16 GEMM + bf16 aggregate
    for (int l = 1; l < 4; ++l) {
        k_gemm_mfma<<<cdiv(N, 64), 256, 0, stream>>>(h, Wt + (size_t)(l - 1) * HID * HID,
                                                     tb, N);
        k_aggregate<<<cdiv(N, 4), 256, 0, stream>>>((const uint4*)tb, rowptr, csr,
                                                    selfn, bl[l], (uint4*)h, N);
    }

    k_gcount_bs<<<1, 128, 0, stream>>>(batch, gcnt, N);
    k_pool<<<cdiv(N, 32), 128, 0, stream>>>(h, batch, gsum, N);
    k_mlp<<<NG, HID, 0, stream>>>(gsum, gcnt, Wr1, br1, Wr2, br2, Wr3, out);

    (void)out_size; (void)n_in;
}

// Round 12
// 514.220 us; speedup vs baseline: 1.8619x; 1.0476x over previous
//
#include <hip/hip_runtime.h>
#include <hip/hip_bf16.h>

#define NN 100000
#define NE 1600000
#define IN_DIM 33
#define HID 128
#define NG 128
#define NCLS 10

using short8 = __attribute__((ext_vector_type(8))) short;
using floatx4 = __attribute__((ext_vector_type(4))) float;

static __device__ __forceinline__ size_t szmul(int a, int b) {
    return (size_t)a * (size_t)b;
}

// bf16 helpers: pack with RNE, unpack via bit ops (cheap: 1 VALU each)
static __device__ __forceinline__ unsigned short f2bf(float f) {
    unsigned u = __float_as_uint(f);
    u += 0x7fffu + ((u >> 16) & 1u);
    return (unsigned short)(u >> 16);
}
static __device__ __forceinline__ float bf_lo(unsigned u) { return __uint_as_float(u << 16); }
static __device__ __forceinline__ float bf_hi(unsigned u) { return __uint_as_float(u & 0xffff0000u); }

// ---------------- init ----------------
__global__ void k_init(int* bucket_cnt, int* bucket_fill, float* gsum) {
    int i = blockIdx.x * blockDim.x + threadIdx.x;
    if (i < 513) { bucket_cnt[i] = 0; bucket_fill[i] = 0; }
    if (i < NG * HID) gsum[i] = 0.0f;
}

// ---------------- binned CSR build ----------------
// bucket = col >> 8 (256 nodes per bucket, nbk = ceil(N/256) = 391)

// Pass A: bucket histogram, LDS-aggregated
__global__ __launch_bounds__(256) void k_bhist(const int* __restrict__ col,
                                               int* __restrict__ bucket_cnt, int e, int nbk) {
    __shared__ int hist[512];
    int tid = threadIdx.x;
    for (int i = tid; i < nbk; i += 256) hist[i] = 0;
    __syncthreads();
    for (int i = blockIdx.x * 256 + tid; i < e; i += 256 * 256)
        atomicAdd(&hist[col[i] >> 8], 1);
    __syncthreads();
    for (int i = tid; i < nbk; i += 256)
        if (hist[i]) atomicAdd(&bucket_cnt[i], hist[i]);
}

// parallel exclusive scan over nb <= 512 elements, in place; data[nb] = total
__global__ void k_scan_small(int* data, int nb) {
    __shared__ int s[512];
    int t = threadIdx.x;
    int v = (t < nb) ? data[t] : 0;
    s[t] = v;
    __syncthreads();
    for (int o = 1; o < 512; o <<= 1) {
        int a = (t >= o) ? s[t - o] : 0;
        __syncthreads();
        s[t] += a;
        __syncthreads();
    }
    if (t < nb) data[t] = s[t] - v;
    if (t == nb - 1) data[nb] = s[t];
}

// Pass C: binned scatter. Each block multisplits 4096 edges by bucket in LDS,
// reserves global space per touched bucket, writes records grouped by bucket.
// Record: x = (col&255)<<17 | src (src < 2^17), y = raw w bits.
__global__ __launch_bounds__(256) void k_bin_scatter(const int* __restrict__ row,
                                                     const int* __restrict__ col,
                                                     const float* __restrict__ w,
                                                     const int* __restrict__ bucket_base,
                                                     int* __restrict__ bucket_fill,
                                                     uint2* __restrict__ binned, int e, int nbk) {
    __shared__ int hist[512], rnk[512], basub[512];
    int tid = threadIdx.x;
    int c0 = blockIdx.x * 4096;
    for (int i = tid; i < nbk; i += 256) { hist[i] = 0; rnk[i] = 0; }
    __syncthreads();
    int myb[16]; unsigned myp[16]; unsigned myw[16];
#pragma unroll
    for (int u = 0; u < 16; ++u) {
        int idx = c0 + u * 256 + tid;
        int b = -1;
        if (idx < e) {
            int c = col[idx];
            int r = row[idx];
            myw[u] = __float_as_uint(w[idx]);
            b = c >> 8;
            myp[u] = ((unsigned)(c & 255) << 17) | (unsigned)r;
            atomicAdd(&hist[b], 1);
        }
        myb[u] = b;
    }
    __syncthreads();
    for (int i = tid; i < nbk; i += 256) {
        int c = hist[i];
        basub[i] = (c > 0) ? (bucket_base[i] + atomicAdd(&bucket_fill[i], c)) : 0;
    }
    __syncthreads();
#pragma unroll
    for (int u = 0; u < 16; ++u) {
        int b = myb[u];
        if (b >= 0) {
            int rk = atomicAdd(&rnk[b], 1);
            binned[basub[b] + rk] = make_uint2(myp[u], myw[u]);
        }
    }
}

// Pass D1: per-bucket node histogram -> cnt (no global atomics)
__global__ __launch_bounds__(256) void k_bucket_cnt(const uint2* __restrict__ binned,
                                                    const int* __restrict__ bucket_base,
                                                    int* __restrict__ cnt, int n) {
    __shared__ int c256[256];
    int b = blockIdx.x, tid = threadIdx.x;
    c256[tid] = 0;
    __syncthreads();
    int beg = bucket_base[b], end = bucket_base[b + 1];
    for (int e2 = beg + tid; e2 < end; e2 += 256)
        atomicAdd(&c256[(binned[e2].x >> 17) & 255], 1);
    __syncthreads();
    int node = b * 256 + tid;
    if (node < n) cnt[node] = c256[tid];
}

#define SCAN_B 1024
__global__ void k_scan1(const int* __restrict__ cnt, int* __restrict__ rowptr,
                        int* __restrict__ bsums, int n) {
    __shared__ int s[SCAN_B];
    int t = threadIdx.x;
    int i = blockIdx.x * SCAN_B + t;
    int v = (i < n) ? cnt[i] : 0;
    s[t] = v;
    __syncthreads();
    for (int o = 1; o < SCAN_B; o <<= 1) {
        int a = (t >= o) ? s[t - o] : 0;
        __syncthreads();
        s[t] += a;
        __syncthreads();
    }
    if (i < n) rowptr[i] = s[t] - v;          // exclusive within block
    if (t == SCAN_B - 1) bsums[blockIdx.x] = s[t];
}

__global__ void k_scan3(int* rowptr, const int* __restrict__ bsums, int n, int etot) {
    int i = blockIdx.x * blockDim.x + threadIdx.x;
    if (i < n) rowptr[i] += bsums[i >> 10];
    else if (i == n) rowptr[n] = etot;
}

// Pass D2: per-bucket final scatter; writes land within the bucket's ~32KB
// CSR extent -> L2-absorbed, full lines to HBM.
__global__ __launch_bounds__(256) void k_bucket_scatter(const uint2* __restrict__ binned,
                                                        const int* __restrict__ bucket_base,
                                                        const int* __restrict__ rowptr,
                                                        int2* __restrict__ csr, int n) {
    __shared__ int f256[256];
    int b = blockIdx.x, tid = threadIdx.x;
    f256[tid] = 0;
    __syncthreads();
    int beg = bucket_base[b], end = bucket_base[b + 1];
    for (int e2 = beg + tid; e2 < end; e2 += 256) {
        uint2 rec = binned[e2];
        int lo = (rec.x >> 17) & 255;
        int node = (b << 8) | lo;
        int src = rec.x & 0x1FFFF;
        int pos = rowptr[node] + atomicAdd(&f256[lo], 1);
        csr[pos] = make_int2(src, (int)rec.y);
    }
    (void)n;
}

// deg[i] = 1 (self loop) + sum of raw weights into i; dinv = deg^-1/2
__global__ void k_deg(const int* __restrict__ rowptr, const int2* __restrict__ csr,
                      float* __restrict__ dinv, float* __restrict__ selfn, int n) {
    int i = blockIdx.x * blockDim.x + threadIdx.x;
    if (i >= n) return;
    int beg = rowptr[i], end = rowptr[i + 1];
    float d = 1.0f;
    for (int e = beg; e < end; ++e) d += __int_as_float(csr[e].y);
    float di = (d > 0.0f) ? (1.0f / sqrtf(d)) : 0.0f;
    dinv[i] = di;
    selfn[i] = di * di;
}

// csr_w[e] = dinv[src]*w*dinv[dst]
__global__ void k_norm(const int* __restrict__ rowptr, int2* __restrict__ csr,
                       const float* __restrict__ dinv, int n) {
    int i = blockIdx.x * blockDim.x + threadIdx.x;
    if (i >= n) return;
    float dc = dinv[i];
    int beg = rowptr[i], end = rowptr[i + 1];
    for (int e = beg; e < end; ++e) {
        int2 v = csr[e];
        float nw = dinv[v.x] * __int_as_float(v.y) * dc;
        csr[e] = make_int2(v.x, __float_as_int(nw));
    }
}

// ---------------- fused weights: M = We@W1 [33x128], v = be@W1 [128] ----------------
__global__ void k_combine(const float* __restrict__ We, const float* __restrict__ W1,
                          const float* __restrict__ be,
                          float* __restrict__ M, float* __restrict__ v) {
    int f = threadIdx.x;            // 128
    int k = blockIdx.x;             // 0..33; 33 => bias row
    if (k < IN_DIM) {
        float a = 0.0f;
#pragma unroll 8
        for (int j = 0; j < HID; ++j) a += We[k * HID + j] * W1[j * HID + f];
        M[k * HID + f] = a;
    } else {
        float a = 0.0f;
#pragma unroll 8
        for (int j = 0; j < HID; ++j) a += be[j] * W1[j * HID + f];
        v[f] = a;
    }
}

// ---------------- W transpose+cast: Wt[l][c][k] = bf16(W_l[k][c]) ----------------
__global__ void k_wcast3(const float* __restrict__ W1, const float* __restrict__ W2,
                         const float* __restrict__ W3, unsigned short* __restrict__ Wt) {
    int k = blockIdx.x, c = threadIdx.x, l = blockIdx.y;
    const float* W = (l == 0) ? W1 : (l == 1) ? W2 : W3;
    Wt[((size_t)l * HID + c) * HID + k] = f2bf(W[k * HID + c]);
}

// ---------------- t = bf16(x@M + v)  (N x 33 @ 33 x 128) ----------------
__global__ __launch_bounds__(256) void k_gemm_x(const float* __restrict__ x,
                                                const float* __restrict__ M,
                                                const float* __restrict__ v,
                                                unsigned short* __restrict__ tb, int n) {
    __shared__ float sX[32 * IN_DIM];
    int n0 = blockIdx.x * 32;
    int tid = threadIdx.x;
    int cnt = n - n0; if (cnt > 32) cnt = 32;
    for (int idx = tid; idx < cnt * IN_DIM; idx += 256)
        sX[idx] = x[szmul(n0, IN_DIM) + idx];
    __syncthreads();
    int f = tid & 127, g = tid >> 7;
    float Mc[IN_DIM];
#pragma unroll
    for (int k = 0; k < IN_DIM; ++k) Mc[k] = M[k * HID + f];
    float vf = v[f];
    int ndEnd = g * 16 + 16; if (ndEnd > cnt) ndEnd = cnt;
    for (int nd = g * 16; nd < ndEnd; ++nd) {
        float a = vf;
#pragma unroll
        for (int k = 0; k < IN_DIM; ++k) a += sX[nd * IN_DIM + k] * Mc[k];
        tb[szmul(n0 + nd, HID) + f] = f2bf(a);
    }
}

// ---------------- MFMA GEMM: T = A @ W  (A: n x 128 bf16, Wt: 128x128 bf16 col-major) ----
__global__ __launch_bounds__(256) void k_gemm_mfma(const unsigned short* __restrict__ A,
                                                   const unsigned short* __restrict__ Wt,
                                                   unsigned short* __restrict__ T, int n) {
    int wave = threadIdx.x >> 6;
    int lane = threadIdx.x & 63;
    int r = lane & 15, kg = lane >> 4;
    int row0 = blockIdx.x * 64 + wave * 16;
    int arow = row0 + r;
    short8 af[4];
#pragma unroll
    for (int kk = 0; kk < 4; ++kk) {
        if (arow < n)
            af[kk] = *reinterpret_cast<const short8*>(A + szmul(arow, HID) + kk * 32 + kg * 8);
        else
            af[kk] = short8{0, 0, 0, 0, 0, 0, 0, 0};
    }
#pragma unroll
    for (int ct = 0; ct < 8; ++ct) {
        floatx4 acc = {0.f, 0.f, 0.f, 0.f};
#pragma unroll
        for (int kk = 0; kk < 4; ++kk) {
            short8 bf = *reinterpret_cast<const short8*>(
                Wt + (size_t)(ct * 16 + r) * HID + kk * 32 + kg * 8);
            acc = __builtin_amdgcn_mfma_f32_16x16x32_bf16(af[kk], bf, acc, 0, 0, 0);
        }
#pragma unroll
        for (int reg = 0; reg < 4; ++reg) {
            int orow = row0 + kg * 4 + reg;
            if (orow < n)
                T[szmul(orow, HID) + ct * 16 + r] = f2bf(acc[reg]);
        }
    }
}

// ---------------- aggregate: h[i] = relu(b + selfn[i]*t[i] + sum_e w_e * t[src_e]) ----
// Group-per-node: 16-lane group owns one node (4 nodes/wave). Each group reads its
// own edge records directly from csr (group-uniform 8B, L1-hit); lane p holds
// features 8p..8p+7 (uint4 = 16B; 16 lanes = full 256B row). No shfl anywhere;
// iterations independent -> unroll 4 keeps ~4 gathers in flight per wave.
__global__ __launch_bounds__(256) void k_aggregate(const uint4* __restrict__ tb,
                                                   const int* __restrict__ rowptr,
                                                   const int2* __restrict__ csr,
                                                   const float* __restrict__ selfn,
                                                   const float* __restrict__ bias,
                                                   uint4* __restrict__ hout, int n) {
    int i = (blockIdx.x * 256 + threadIdx.x) >> 4;   // node per 16-lane group
    if (i >= n) return;
    int p = threadIdx.x & 15;                 // uint4 index in row; features 8p..8p+7
    uint4 sv = tb[szmul(i, 16) + p];
    float sn = selfn[i];
    const float4* bp = reinterpret_cast<const float4*>(bias + p * 8);
    float4 b0 = bp[0], b1 = bp[1];
    float a0 = b0.x + sn * bf_lo(sv.x), a1 = b0.y + sn * bf_hi(sv.x);
    float a2 = b0.z + sn * bf_lo(sv.y), a3 = b0.w + sn * bf_hi(sv.y);
    float a4 = b1.x + sn * bf_lo(sv.z), a5 = b1.y + sn * bf_hi(sv.z);
    float a6 = b1.z + sn * bf_lo(sv.w), a7 = b1.w + sn * bf_hi(sv.w);
    int beg = rowptr[i], end = rowptr[i + 1];
#pragma unroll 4
    for (int j = beg; j < end; ++j) {
        int2 e = csr[j];                      // uniform within group -> broadcast
        float wj = __int_as_float(e.y);
        uint4 r = tb[szmul(e.x, 16) + p];
        a0 += wj * bf_lo(r.x); a1 += wj * bf_hi(r.x);
        a2 += wj * bf_lo(r.y); a3 += wj * bf_hi(r.y);
        a4 += wj * bf_lo(r.z); a5 += wj * bf_hi(r.z);
        a6 += wj * bf_lo(r.w); a7 += wj * bf_hi(r.w);
    }
    unsigned u0 = (unsigned)f2bf(fmaxf(a0, 0.f)) | ((unsigned)f2bf(fmaxf(a1, 0.f)) << 16);
    unsigned u1 = (unsigned)f2bf(fmaxf(a2, 0.f)) | ((unsigned)f2bf(fmaxf(a3, 0.f)) << 16);
    unsigned u2 = (unsigned)f2bf(fmaxf(a4, 0.f)) | ((unsigned)f2bf(fmaxf(a5, 0.f)) << 16);
    unsigned u3 = (unsigned)f2bf(fmaxf(a6, 0.f)) | ((unsigned)f2bf(fmaxf(a7, 0.f)) << 16);
    hout[szmul(i, 16) + p] = make_uint4(u0, u1, u2, u3);
}

// ---------------- pooling ----------------
__global__ void k_gcount_bs(const int* __restrict__ batch, int* gcnt, int n) {
    int g = threadIdx.x;
    if (g >= NG) return;
    int lo = 0, hi = n;
    while (lo < hi) { int mid = (lo + hi) >> 1; if (batch[mid] < g) lo = mid + 1; else hi = mid; }
    int start = lo;
    lo = 0; hi = n;
    while (lo < hi) { int mid = (lo + hi) >> 1; if (batch[mid] < g + 1) lo = mid + 1; else hi = mid; }
    gcnt[g] = lo - start;
}

__global__ __launch_bounds__(128) void k_pool(const unsigned short* __restrict__ h,
                                              const int* __restrict__ batch,
                                              float* gsum, int n) {
    int f = threadIdx.x;
    int i0 = blockIdx.x * 32;
    int i1 = min(i0 + 32, n);
    if (i0 >= n) return;
    float acc = 0.0f;
    int cur = batch[i0];
    for (int i = i0; i < i1; ++i) {
        int g = batch[i];
        if (g != cur) { atomicAdd(&gsum[cur * HID + f], acc); acc = 0.0f; cur = g; }
        acc += __uint_as_float((unsigned)h[szmul(i, HID) + f] << 16);
    }
    atomicAdd(&gsum[cur * HID + f], acc);
}

// ---------------- readout MLP ----------------
__global__ __launch_bounds__(128) void k_mlp(const float* __restrict__ gsum,
                                             const int* __restrict__ gcnt,
                                             const float* __restrict__ Wr1, const float* __restrict__ br1,
                                             const float* __restrict__ Wr2, const float* __restrict__ br2,
                                             const float* __restrict__ Wr3,
                                             float* __restrict__ out) {
    int g = blockIdx.x;
    int t = threadIdx.x;
    __shared__ float p[HID];
    __shared__ float r1[64];
    __shared__ float r2[32];
    float c = fmaxf((float)gcnt[g], 1.0f);
    p[t] = gsum[g * HID + t] / c;
    __syncthreads();
    if (t < 64) {
        float a = br1[t];
#pragma unroll 8
        for (int k = 0; k < HID; ++k) a += p[k] * Wr1[k * 64 + t];
        r1[t] = fmaxf(a, 0.0f);
    }
    __syncthreads();
    if (t < 32) {
        float a = br2[t];
#pragma unroll 8
        for (int k = 0; k < 64; ++k) a += r1[k] * Wr2[k * 32 + t];
        r2[t] = fmaxf(a, 0.0f);
    }
    __syncthreads();
    if (t < NCLS) {
        float a = 0.0f;
#pragma unroll
        for (int k = 0; k < 32; ++k) a += r2[k] * Wr3[k * NCLS + t];
        out[g * NCLS + t] = a;
    }
}

extern "C" void kernel_launch(void* const* d_in, const int* in_sizes, int n_in,
                              void* d_out, int out_size, void* d_ws, size_t ws_size,
                              hipStream_t stream) {
    const float* x     = (const float*)d_in[0];
    const int*   ei    = (const int*)d_in[1];
    const float* ew    = (const float*)d_in[2];
    const int*   batch = (const int*)d_in[3];
    const float* We  = (const float*)d_in[4];
    const float* be  = (const float*)d_in[5];
    const float* Wl[4] = { (const float*)d_in[6], (const float*)d_in[8],
                           (const float*)d_in[10], (const float*)d_in[12] };
    const float* bl[4] = { (const float*)d_in[7], (const float*)d_in[9],
                           (const float*)d_in[11], (const float*)d_in[13] };
    const float* Wr1 = (const float*)d_in[14];
    const float* br1 = (const float*)d_in[15];
    const float* Wr2 = (const float*)d_in[16];
    const float* br2 = (const float*)d_in[17];
    const float* Wr3 = (const float*)d_in[18];
    float* out = (float*)d_out;

    const int N = in_sizes[3];      // 100000
    const int E = in_sizes[2];      // 1600000
    const int* row = ei;
    const int* col = ei + E;
    const int nbk = (N + 255) >> 8; // 391 buckets

    // workspace layout
    char* w = (char*)d_ws;
    size_t off = 0;
    auto alloc = [&](size_t bytes) -> void* {
        void* p = w + off;
        off = (off + bytes + 255) & ~(size_t)255;
        return p;
    };
    float* dinv       = (float*)alloc((size_t)N * 4);
    float* selfn      = (float*)alloc((size_t)N * 4);
    int*   cnt        = (int*)  alloc((size_t)N * 4);
    int*   rowptr     = (int*)  alloc((size_t)(N + 1) * 4);
    int*   bsums      = (int*)  alloc(4096);
    int*   bucket_cnt = (int*)  alloc(513 * 4);   // becomes bucket_base after scan
    int*   bucket_fill= (int*)  alloc(513 * 4);
    int2*  csr        = (int2*) alloc((size_t)E * 8);
    unsigned short* h  = (unsigned short*)alloc((size_t)N * HID * 2);  // bf16 activations
    unsigned short* tb = (unsigned short*)alloc((size_t)N * HID * 2);  // bf16 messages
    unsigned short* Wt = (unsigned short*)alloc((size_t)3 * HID * HID * 2); // bf16 W^T x3
    float* M          = (float*)alloc((size_t)IN_DIM * HID * 4);
    float* vbe        = (float*)alloc((size_t)HID * 4);
    float* gsum       = (float*)alloc((size_t)NG * HID * 4);
    int*   gcnt       = (int*)  alloc((size_t)NG * 4);
    uint2* binned     = (uint2*)tb;  // alias: consumed by D1/D2 before tb first written
    (void)ws_size;

    auto cdiv = [](int a, int b) { return (a + b - 1) / b; };

    // ---- binned CSR build ----
    k_init<<<64, 256, 0, stream>>>(bucket_cnt, bucket_fill, gsum);
    k_bhist<<<256, 256, 0, stream>>>(col, bucket_cnt, E, nbk);
    k_scan_small<<<1, 512, 0, stream>>>(bucket_cnt, nbk);        // -> bucket_base
    k_bin_scatter<<<cdiv(E, 4096), 256, 0, stream>>>(row, col, ew, bucket_cnt,
                                                     bucket_fill, binned, E, nbk);
    k_bucket_cnt<<<nbk, 256, 0, stream>>>(binned, bucket_cnt, cnt, N);

    int nb = cdiv(N, SCAN_B);
    k_scan1<<<nb, SCAN_B, 0, stream>>>(cnt, rowptr, bsums, N);
    k_scan_small<<<1, 512, 0, stream>>>(bsums, nb);
    k_scan3<<<cdiv(N + 1, 256), 256, 0, stream>>>(rowptr, bsums, N, E);
    k_bucket_scatter<<<nbk, 256, 0, stream>>>(binned, bucket_cnt, rowptr, csr, N);

    k_deg<<<cdiv(N, 256), 256, 0, stream>>>(rowptr, csr, dinv, selfn, N);
    k_norm<<<cdiv(N, 256), 256, 0, stream>>>(rowptr, csr, dinv, N);

    // fused layer-1 weights + bf16 transposed W for layers 2-4
    k_combine<<<IN_DIM + 1, HID, 0, stream>>>(We, Wl[0], be, M, vbe);
    k_wcast3<<<dim3(HID, 3), HID, 0, stream>>>(Wl[1], Wl[2], Wl[3], Wt);

    // layer 1: t = bf16(x@(We@W1) + be@W1); h = relu(agg(t) + b1)
    k_gemm_x<<<cdiv(N, 32), 256, 0, stream>>>(x, M, vbe, tb, N);
    k_aggregate<<<cdiv(N, 16), 256, 0, stream>>>((const uint4*)tb, rowptr, csr,
                                                 selfn, bl[0], (uint4*)h, N);

    // layers 2-4: MFMA bf16 GEMM + bf16 aggregate
    for (int l = 1; l < 4; ++l) {
        k_gemm_mfma<<<cdiv(N, 64), 256, 0, stream>>>(h, Wt + (size_t)(l - 1) * HID * HID,
                                                     tb, N);
        k_aggregate<<<cdiv(N, 16), 256, 0, stream>>>((const uint4*)tb, rowptr, csr,
                                                     selfn, bl[l], (uint4*)h, N);
    }

    k_gcount_bs<<<1, 128, 0, stream>>>(batch, gcnt, N);
    k_pool<<<cdiv(N, 32), 128, 0, stream>>>(h, batch, gsum, N);
    k_mlp<<<NG, HID, 0, stream>>>(gsum, gcnt, Wr1, br1, Wr2, br2, Wr3, out);

    (void)out_size; (void)n_in;
}

// Round 13
// 500.702 us; speedup vs baseline: 1.9121x; 1.0270x over previous
//
#include <hip/hip_runtime.h>
#include <hip/hip_bf16.h>

#define NN 100000
#define NE 1600000
#define IN_DIM 33
#define HID 128
#define NG 128
#define NCLS 10

using short8 = __attribute__((ext_vector_type(8))) short;
using floatx4 = __attribute__((ext_vector_type(4))) float;

static __device__ __forceinline__ size_t szmul(int a, int b) {
    return (size_t)a * (size_t)b;
}

// bf16 helpers: pack with RNE, unpack via bit ops (cheap: 1 VALU each)
static __device__ __forceinline__ unsigned short f2bf(float f) {
    unsigned u = __float_as_uint(f);
    u += 0x7fffu + ((u >> 16) & 1u);
    return (unsigned short)(u >> 16);
}
static __device__ __forceinline__ float bf_lo(unsigned u) { return __uint_as_float(u << 16); }
static __device__ __forceinline__ float bf_hi(unsigned u) { return __uint_as_float(u & 0xffff0000u); }

// ---------------- init ----------------
__global__ void k_init(int* bucket_cnt, int* bucket_fill, float* gsum) {
    int i = blockIdx.x * blockDim.x + threadIdx.x;
    if (i < 513) { bucket_cnt[i] = 0; bucket_fill[i] = 0; }
    if (i < NG * HID) gsum[i] = 0.0f;
}

// ---------------- binned CSR build ----------------
// bucket = col >> 8 (256 nodes per bucket, nbk = ceil(N/256) = 391)

// Pass A: bucket histogram, LDS-aggregated
__global__ __launch_bounds__(256) void k_bhist(const int* __restrict__ col,
                                               int* __restrict__ bucket_cnt, int e, int nbk) {
    __shared__ int hist[512];
    int tid = threadIdx.x;
    for (int i = tid; i < nbk; i += 256) hist[i] = 0;
    __syncthreads();
    for (int i = blockIdx.x * 256 + tid; i < e; i += 256 * 256)
        atomicAdd(&hist[col[i] >> 8], 1);
    __syncthreads();
    for (int i = tid; i < nbk; i += 256)
        if (hist[i]) atomicAdd(&bucket_cnt[i], hist[i]);
}

// parallel exclusive scan over nb <= 512 elements, in place; data[nb] = total
__global__ void k_scan_small(int* data, int nb) {
    __shared__ int s[512];
    int t = threadIdx.x;
    int v = (t < nb) ? data[t] : 0;
    s[t] = v;
    __syncthreads();
    for (int o = 1; o < 512; o <<= 1) {
        int a = (t >= o) ? s[t - o] : 0;
        __syncthreads();
        s[t] += a;
        __syncthreads();
    }
    if (t < nb) data[t] = s[t] - v;
    if (t == nb - 1) data[nb] = s[t];
}

// Pass C: binned scatter. Each block multisplits 4096 edges by bucket in LDS,
// reserves global space per touched bucket, writes records grouped by bucket.
// Record: x = (col&255)<<17 | src (src < 2^17), y = raw w bits.
__global__ __launch_bounds__(256) void k_bin_scatter(const int* __restrict__ row,
                                                     const int* __restrict__ col,
                                                     const float* __restrict__ w,
                                                     const int* __restrict__ bucket_base,
                                                     int* __restrict__ bucket_fill,
                                                     uint2* __restrict__ binned, int e, int nbk) {
    __shared__ int hist[512], rnk[512], basub[512];
    int tid = threadIdx.x;
    int c0 = blockIdx.x * 4096;
    for (int i = tid; i < nbk; i += 256) { hist[i] = 0; rnk[i] = 0; }
    __syncthreads();
    int myb[16]; unsigned myp[16]; unsigned myw[16];
#pragma unroll
    for (int u = 0; u < 16; ++u) {
        int idx = c0 + u * 256 + tid;
        int b = -1;
        if (idx < e) {
            int c = col[idx];
            int r = row[idx];
            myw[u] = __float_as_uint(w[idx]);
            b = c >> 8;
            myp[u] = ((unsigned)(c & 255) << 17) | (unsigned)r;
            atomicAdd(&hist[b], 1);
        }
        myb[u] = b;
    }
    __syncthreads();
    for (int i = tid; i < nbk; i += 256) {
        int c = hist[i];
        basub[i] = (c > 0) ? (bucket_base[i] + atomicAdd(&bucket_fill[i], c)) : 0;
    }
    __syncthreads();
#pragma unroll
    for (int u = 0; u < 16; ++u) {
        int b = myb[u];
        if (b >= 0) {
            int rk = atomicAdd(&rnk[b], 1);
            binned[basub[b] + rk] = make_uint2(myp[u], myw[u]);
        }
    }
}

// Pass D1: per-bucket node histogram + raw weight sums -> cnt, wsum (no global atomics)
__global__ __launch_bounds__(256) void k_bucket_cnt(const uint2* __restrict__ binned,
                                                    const int* __restrict__ bucket_base,
                                                    int* __restrict__ cnt,
                                                    float* __restrict__ wsum, int n) {
    __shared__ int c256[256];
    __shared__ float s256[256];
    int b = blockIdx.x, tid = threadIdx.x;
    c256[tid] = 0;
    s256[tid] = 0.0f;
    __syncthreads();
    int beg = bucket_base[b], end = bucket_base[b + 1];
    for (int e2 = beg + tid; e2 < end; e2 += 256) {
        uint2 rec = binned[e2];
        int lo = (rec.x >> 17) & 255;
        atomicAdd(&c256[lo], 1);
        atomicAdd(&s256[lo], __uint_as_float(rec.y));
    }
    __syncthreads();
    int node = b * 256 + tid;
    if (node < n) { cnt[node] = c256[tid]; wsum[node] = s256[tid]; }
}

// dinv/selfn from wsum (in place on dinv buffer)
__global__ void k_dinv(float* __restrict__ dinv, float* __restrict__ selfn, int n) {
    int i = blockIdx.x * blockDim.x + threadIdx.x;
    if (i >= n) return;
    float d = 1.0f + dinv[i];
    float di = (d > 0.0f) ? (1.0f / sqrtf(d)) : 0.0f;
    dinv[i] = di;
    selfn[i] = di * di;
}

#define SCAN_B 1024
__global__ void k_scan1(const int* __restrict__ cnt, int* __restrict__ rowptr,
                        int* __restrict__ bsums, int n) {
    __shared__ int s[SCAN_B];
    int t = threadIdx.x;
    int i = blockIdx.x * SCAN_B + t;
    int v = (i < n) ? cnt[i] : 0;
    s[t] = v;
    __syncthreads();
    for (int o = 1; o < SCAN_B; o <<= 1) {
        int a = (t >= o) ? s[t - o] : 0;
        __syncthreads();
        s[t] += a;
        __syncthreads();
    }
    if (i < n) rowptr[i] = s[t] - v;          // exclusive within block
    if (t == SCAN_B - 1) bsums[blockIdx.x] = s[t];
}

__global__ void k_scan3(int* rowptr, const int* __restrict__ bsums, int n, int etot) {
    int i = blockIdx.x * blockDim.x + threadIdx.x;
    if (i < n) rowptr[i] += bsums[i >> 10];
    else if (i == n) rowptr[n] = etot;
}

// Pass D2: per-bucket final scatter with normalization folded in; writes land
// within the bucket's ~32KB CSR extent -> L2-absorbed, full lines to HBM.
__global__ __launch_bounds__(256) void k_bucket_scatter(const uint2* __restrict__ binned,
                                                        const int* __restrict__ bucket_base,
                                                        const int* __restrict__ rowptr,
                                                        const float* __restrict__ dinv,
                                                        int2* __restrict__ csr, int n) {
    __shared__ int f256[256];
    int b = blockIdx.x, tid = threadIdx.x;
    f256[tid] = 0;
    __syncthreads();
    int beg = bucket_base[b], end = bucket_base[b + 1];
    for (int e2 = beg + tid; e2 < end; e2 += 256) {
        uint2 rec = binned[e2];
        int lo = (rec.x >> 17) & 255;
        int node = (b << 8) | lo;
        int src = rec.x & 0x1FFFF;
        float nw = dinv[src] * __uint_as_float(rec.y) * dinv[node];
        int pos = rowptr[node] + atomicAdd(&f256[lo], 1);
        csr[pos] = make_int2(src, __float_as_int(nw));
    }
    (void)n;
}

// ---------------- fused weights: M = We@W1 [33x128], v = be@W1 [128] ----------------
__global__ void k_combine(const float* __restrict__ We, const float* __restrict__ W1,
                          const float* __restrict__ be,
                          float* __restrict__ M, float* __restrict__ v) {
    int f = threadIdx.x;            // 128
    int k = blockIdx.x;             // 0..33; 33 => bias row
    if (k < IN_DIM) {
        float a = 0.0f;
#pragma unroll 8
        for (int j = 0; j < HID; ++j) a += We[k * HID + j] * W1[j * HID + f];
        M[k * HID + f] = a;
    } else {
        float a = 0.0f;
#pragma unroll 8
        for (int j = 0; j < HID; ++j) a += be[j] * W1[j * HID + f];
        v[f] = a;
    }
}

// ---------------- W transpose+cast: Wt[l][c][k] = bf16(W_l[k][c]) ----------------
__global__ void k_wcast3(const float* __restrict__ W1, const float* __restrict__ W2,
                         const float* __restrict__ W3, unsigned short* __restrict__ Wt) {
    int k = blockIdx.x, c = threadIdx.x, l = blockIdx.y;
    const float* W = (l == 0) ? W1 : (l == 1) ? W2 : W3;
    Wt[((size_t)l * HID + c) * HID + k] = f2bf(W[k * HID + c]);
}

// ---------------- t = bf16(x@M + v)  (N x 33 @ 33 x 128) ----------------
__global__ __launch_bounds__(256) void k_gemm_x(const float* __restrict__ x,
                                                const float* __restrict__ M,
                                                const float* __restrict__ v,
                                                unsigned short* __restrict__ tb, int n) {
    __shared__ float sX[32 * IN_DIM];
    int n0 = blockIdx.x * 32;
    int tid = threadIdx.x;
    int cnt = n - n0; if (cnt > 32) cnt = 32;
    for (int idx = tid; idx < cnt * IN_DIM; idx += 256)
        sX[idx] = x[szmul(n0, IN_DIM) + idx];
    __syncthreads();
    int f = tid & 127, g = tid >> 7;
    float Mc[IN_DIM];
#pragma unroll
    for (int k = 0; k < IN_DIM; ++k) Mc[k] = M[k * HID + f];
    float vf = v[f];
    int ndEnd = g * 16 + 16; if (ndEnd > cnt) ndEnd = cnt;
    for (int nd = g * 16; nd < ndEnd; ++nd) {
        float a = vf;
#pragma unroll
        for (int k = 0; k < IN_DIM; ++k) a += sX[nd * IN_DIM + k] * Mc[k];
        tb[szmul(n0 + nd, HID) + f] = f2bf(a);
    }
}

// ---------------- MFMA GEMM: T = A @ W  (A: n x 128 bf16, Wt: 128x128 bf16 col-major) ----
// 4 waves/block, wave = 16 rows x 128 cols; no LDS. Loop order kk-outer/ct-inner
// gives 8 INDEPENDENT accumulator chains (acc[ct]) -> MFMA issue-limited, not
// latency-limited. acc[] fully unrolled, static indices only.
__global__ __launch_bounds__(256) void k_gemm_mfma(const unsigned short* __restrict__ A,
                                                   const unsigned short* __restrict__ Wt,
                                                   unsigned short* __restrict__ T, int n) {
    int wave = threadIdx.x >> 6;
    int lane = threadIdx.x & 63;
    int r = lane & 15, kg = lane >> 4;
    int row0 = blockIdx.x * 64 + wave * 16;
    int arow = row0 + r;
    short8 af[4];
#pragma unroll
    for (int kk = 0; kk < 4; ++kk) {
        if (arow < n)
            af[kk] = *reinterpret_cast<const short8*>(A + szmul(arow, HID) + kk * 32 + kg * 8);
        else
            af[kk] = short8{0, 0, 0, 0, 0, 0, 0, 0};
    }
    floatx4 acc[8];
#pragma unroll
    for (int ct = 0; ct < 8; ++ct) acc[ct] = floatx4{0.f, 0.f, 0.f, 0.f};
#pragma unroll
    for (int kk = 0; kk < 4; ++kk) {
#pragma unroll
        for (int ct = 0; ct < 8; ++ct) {
            short8 bf = *reinterpret_cast<const short8*>(
                Wt + (size_t)(ct * 16 + r) * HID + kk * 32 + kg * 8);
            acc[ct] = __builtin_amdgcn_mfma_f32_16x16x32_bf16(af[kk], bf, acc[ct], 0, 0, 0);
        }
    }
#pragma unroll
    for (int ct = 0; ct < 8; ++ct) {
#pragma unroll
        for (int reg = 0; reg < 4; ++reg) {
            int orow = row0 + kg * 4 + reg;
            if (orow < n)
                T[szmul(orow, HID) + ct * 16 + r] = f2bf(acc[ct][reg]);
        }
    }
}

// ---------------- aggregate: h[i] = relu(b + selfn[i]*t[i] + sum_e w_e * t[src_e]) ----
// Group-per-node: 16-lane group owns one node (4 nodes/wave). Each group reads its
// own edge records directly from csr (group-uniform 8B, L1-hit); lane p holds
// features 8p..8p+7 (uint4 = 16B; 16 lanes = full 256B row). No shfl anywhere.
__global__ __launch_bounds__(256) void k_aggregate(const uint4* __restrict__ tb,
                                                   const int* __restrict__ rowptr,
                                                   const int2* __restrict__ csr,
                                                   const float* __restrict__ selfn,
                                                   const float* __restrict__ bias,
                                                   uint4* __restrict__ hout, int n) {
    int i = (blockIdx.x * 256 + threadIdx.x) >> 4;   // node per 16-lane group
    if (i >= n) return;
    int p = threadIdx.x & 15;                 // uint4 index in row; features 8p..8p+7
    uint4 sv = tb[szmul(i, 16) + p];
    float sn = selfn[i];
    const float4* bp = reinterpret_cast<const float4*>(bias + p * 8);
    float4 b0 = bp[0], b1 = bp[1];
    float a0 = b0.x + sn * bf_lo(sv.x), a1 = b0.y + sn * bf_hi(sv.x);
    float a2 = b0.z + sn * bf_lo(sv.y), a3 = b0.w + sn * bf_hi(sv.y);
    float a4 = b1.x + sn * bf_lo(sv.z), a5 = b1.y + sn * bf_hi(sv.z);
    float a6 = b1.z + sn * bf_lo(sv.w), a7 = b1.w + sn * bf_hi(sv.w);
    int beg = rowptr[i], end = rowptr[i + 1];
#pragma unroll 4
    for (int j = beg; j < end; ++j) {
        int2 e = csr[j];                      // uniform within group -> broadcast
        float wj = __int_as_float(e.y);
        uint4 r = tb[szmul(e.x, 16) + p];
        a0 += wj * bf_lo(r.x); a1 += wj * bf_hi(r.x);
        a2 += wj * bf_lo(r.y); a3 += wj * bf_hi(r.y);
        a4 += wj * bf_lo(r.z); a5 += wj * bf_hi(r.z);
        a6 += wj * bf_lo(r.w); a7 += wj * bf_hi(r.w);
    }
    unsigned u0 = (unsigned)f2bf(fmaxf(a0, 0.f)) | ((unsigned)f2bf(fmaxf(a1, 0.f)) << 16);
    unsigned u1 = (unsigned)f2bf(fmaxf(a2, 0.f)) | ((unsigned)f2bf(fmaxf(a3, 0.f)) << 16);
    unsigned u2 = (unsigned)f2bf(fmaxf(a4, 0.f)) | ((unsigned)f2bf(fmaxf(a5, 0.f)) << 16);
    unsigned u3 = (unsigned)f2bf(fmaxf(a6, 0.f)) | ((unsigned)f2bf(fmaxf(a7, 0.f)) << 16);
    hout[szmul(i, 16) + p] = make_uint4(u0, u1, u2, u3);
}

// ---------------- pooling ----------------
__global__ void k_gcount_bs(const int* __restrict__ batch, int* gcnt, int n) {
    int g = threadIdx.x;
    if (g >= NG) return;
    int lo = 0, hi = n;
    while (lo < hi) { int mid = (lo + hi) >> 1; if (batch[mid] < g) lo = mid + 1; else hi = mid; }
    int start = lo;
    lo = 0; hi = n;
    while (lo < hi) { int mid = (lo + hi) >> 1; if (batch[mid] < g + 1) lo = mid + 1; else hi = mid; }
    gcnt[g] = lo - start;
}

__global__ __launch_bounds__(128) void k_pool(const unsigned short* __restrict__ h,
                                              const int* __restrict__ batch,
                                              float* gsum, int n) {
    int f = threadIdx.x;
    int i0 = blockIdx.x * 32;
    int i1 = min(i0 + 32, n);
    if (i0 >= n) return;
    float acc = 0.0f;
    int cur = batch[i0];
    for (int i = i0; i < i1; ++i) {
        int g = batch[i];
        if (g != cur) { atomicAdd(&gsum[cur * HID + f], acc); acc = 0.0f; cur = g; }
        acc += __uint_as_float((unsigned)h[szmul(i, HID) + f] << 16);
    }
    atomicAdd(&gsum[cur * HID + f], acc);
}

// ---------------- readout MLP ----------------
__global__ __launch_bounds__(128) void k_mlp(const float* __restrict__ gsum,
                                             const int* __restrict__ gcnt,
                                             const float* __restrict__ Wr1, const float* __restrict__ br1,
                                             const float* __restrict__ Wr2, const float* __restrict__ br2,
                                             const float* __restrict__ Wr3,
                                             float* __restrict__ out) {
    int g = blockIdx.x;
    int t = threadIdx.x;
    __shared__ float p[HID];
    __shared__ float r1[64];
    __shared__ float r2[32];
    float c = fmaxf((float)gcnt[g], 1.0f);
    p[t] = gsum[g * HID + t] / c;
    __syncthreads();
    if (t < 64) {
        float a = br1[t];
#pragma unroll 8
        for (int k = 0; k < HID; ++k) a += p[k] * Wr1[k * 64 + t];
        r1[t] = fmaxf(a, 0.0f);
    }
    __syncthreads();
    if (t < 32) {
        float a = br2[t];
#pragma unroll 8
        for (int k = 0; k < 64; ++k) a += r1[k] * Wr2[k * 32 + t];
        r2[t] = fmaxf(a, 0.0f);
    }
    __syncthreads();
    if (t < NCLS) {
        float a = 0.0f;
#pragma unroll
        for (int k = 0; k < 32; ++k) a += r2[k] * Wr3[k * NCLS + t];
        out[g * NCLS + t] = a;
    }
}

extern "C" void kernel_launch(void* const* d_in, const int* in_sizes, int n_in,
                              void* d_out, int out_size, void* d_ws, size_t ws_size,
                              hipStream_t stream) {
    const float* x     = (const float*)d_in[0];
    const int*   ei    = (const int*)d_in[1];
    const float* ew    = (const float*)d_in[2];
    const int*   batch = (const int*)d_in[3];
    const float* We  = (const float*)d_in[4];
    const float* be  = (const float*)d_in[5];
    const float* Wl[4] = { (const float*)d_in[6], (const float*)d_in[8],
                           (const float*)d_in[10], (const float*)d_in[12] };
    const float* bl[4] = { (const float*)d_in[7], (const float*)d_in[9],
                           (const float*)d_in[11], (const float*)d_in[13] };
    const float* Wr1 = (const float*)d_in[14];
    const float* br1 = (const float*)d_in[15];
    const float* Wr2 = (const float*)d_in[16];
    const float* br2 = (const float*)d_in[17];
    const float* Wr3 = (const float*)d_in[18];
    float* out = (float*)d_out;

    const int N = in_sizes[3];      // 100000
    const int E = in_sizes[2];      // 1600000
    const int* row = ei;
    const int* col = ei + E;
    const int nbk = (N + 255) >> 8; // 391 buckets

    // workspace layout
    char* w = (char*)d_ws;
    size_t off = 0;
    auto alloc = [&](size_t bytes) -> void* {
        void* p = w + off;
        off = (off + bytes + 255) & ~(size_t)255;
        return p;
    };
    float* dinv       = (float*)alloc((size_t)N * 4);   // wsum, then dinv in place
    float* selfn      = (float*)alloc((size_t)N * 4);
    int*   cnt        = (int*)  alloc((size_t)N * 4);
    int*   rowptr     = (int*)  alloc((size_t)(N + 1) * 4);
    int*   bsums      = (int*)  alloc(4096);
    int*   bucket_cnt = (int*)  alloc(513 * 4);   // becomes bucket_base after scan
    int*   bucket_fill= (int*)  alloc(513 * 4);
    int2*  csr        = (int2*) alloc((size_t)E * 8);
    unsigned short* h  = (unsigned short*)alloc((size_t)N * HID * 2);  // bf16 activations
    unsigned short* tb = (unsigned short*)alloc((size_t)N * HID * 2);  // bf16 messages
    unsigned short* Wt = (unsigned short*)alloc((size_t)3 * HID * HID * 2); // bf16 W^T x3
    float* M          = (float*)alloc((size_t)IN_DIM * HID * 4);
    float* vbe        = (float*)alloc((size_t)HID * 4);
    float* gsum       = (float*)alloc((size_t)NG * HID * 4);
    int*   gcnt       = (int*)  alloc((size_t)NG * 4);
    uint2* binned     = (uint2*)tb;  // alias: consumed by D1/D2 before tb first written
    (void)ws_size;

    auto cdiv = [](int a, int b) { return (a + b - 1) / b; };

    // ---- binned CSR build (deg/norm folded in) ----
    k_init<<<64, 256, 0, stream>>>(bucket_cnt, bucket_fill, gsum);
    k_bhist<<<256, 256, 0, stream>>>(col, bucket_cnt, E, nbk);
    k_scan_small<<<1, 512, 0, stream>>>(bucket_cnt, nbk);        // -> bucket_base
    k_bin_scatter<<<cdiv(E, 4096), 256, 0, stream>>>(row, col, ew, bucket_cnt,
                                                     bucket_fill, binned, E, nbk);
    k_bucket_cnt<<<nbk, 256, 0, stream>>>(binned, bucket_cnt, cnt, dinv, N);
    k_dinv<<<cdiv(N, 256), 256, 0, stream>>>(dinv, selfn, N);

    int nb = cdiv(N, SCAN_B);
    k_scan1<<<nb, SCAN_B, 0, stream>>>(cnt, rowptr, bsums, N);
    k_scan_small<<<1, 512, 0, stream>>>(bsums, nb);
    k_scan3<<<cdiv(N + 1, 256), 256, 0, stream>>>(rowptr, bsums, N, E);
    k_bucket_scatter<<<nbk, 256, 0, stream>>>(binned, bucket_cnt, rowptr, dinv, csr, N);

    // fused layer-1 weights + bf16 transposed W for layers 2-4
    k_combine<<<IN_DIM + 1, HID, 0, stream>>>(We, Wl[0], be, M, vbe);
    k_wcast3<<<dim3(HID, 3), HID, 0, stream>>>(Wl[1], Wl[2], Wl[3], Wt);

    // layer 1: t = bf16(x@(We@W1) + be@W1); h = relu(agg(t) + b1)
    k_gemm_x<<<cdiv(N, 32), 256, 0, stream>>>(x, M, vbe, tb, N);
    k_aggregate<<<cdiv(N, 16), 256, 0, stream>>>((const uint4*)tb, rowptr, csr,
                                                 selfn, bl[0], (uint4*)h, N);

    // layers 2-4: MFMA bf16 GEMM + bf16 aggregate
    for (int l = 1; l < 4; ++l) {
        k_gemm_mfma<<<cdiv(N, 64), 256, 0, stream>>>(h, Wt + (size_t)(l - 1) * HID * HID,
                                                     tb, N);
        k_aggregate<<<cdiv(N, 16), 256, 0, stream>>>((const uint4*)tb, rowptr, csr,
                                                     selfn, bl[l], (uint4*)h, N);
    }

    k_gcount_bs<<<1, 128, 0, stream>>>(batch, gcnt, N);
    k_pool<<<cdiv(N, 32), 128, 0, stream>>>(h, batch, gsum, N);
    k_mlp<<<NG, HID, 0, stream>>>(gsum, gcnt, Wr1, br1, Wr2, br2, Wr3, out);

    (void)out_size; (void)n_in;
}